// Round 1
// baseline (474.560 us; speedup 1.0000x reference)
//
#include <hip/hip_runtime.h>
#include <hip/hip_bf16.h>

#define BATCH 4
#define LSEQ 4096
#define DMODEL 1024
#define NHEAD 16
#define RDIM 30
#define DKH 64
#define NCHUNK 16
#define CHUNK 256

typedef __attribute__((ext_vector_type(8))) short bf16x8_t;
typedef __attribute__((ext_vector_type(4))) float f32x4_t;

static __device__ __forceinline__ unsigned short f2bf(float f) {
    __hip_bfloat16 h = __float2bfloat16(f);
    unsigned short u;
    __builtin_memcpy(&u, &h, 2);
    return u;
}

// ---------------- convert f32 -> bf16 (vectorized) ----------------
__global__ void cvt_bf16_kernel(const float* __restrict__ in, unsigned short* __restrict__ out, int n4) {
    int i = blockIdx.x * blockDim.x + threadIdx.x;
    int stride = gridDim.x * blockDim.x;
    for (; i < n4; i += stride) {
        float4 v = ((const float4*)in)[i];
        ushort4 o;
        o.x = f2bf(v.x); o.y = f2bf(v.y); o.z = f2bf(v.z); o.w = f2bf(v.w);
        ((ushort4*)out)[i] = o;
    }
}

// ---------------- transpose + convert: W (K,N) f32 -> Wt (N,K) bf16 ----------------
__global__ void transpose_cvt_kernel(const float* __restrict__ W, unsigned short* __restrict__ outT,
                                     int Kd, int Nd) {
    __shared__ float tile[32][33];
    int n0 = blockIdx.x * 32, k0 = blockIdx.y * 32;
    int tx = threadIdx.x, ty = threadIdx.y;
    #pragma unroll
    for (int r = ty; r < 32; r += 8)
        tile[r][tx] = W[(size_t)(k0 + r) * Nd + n0 + tx];
    __syncthreads();
    #pragma unroll
    for (int r = ty; r < 32; r += 8)
        outT[(size_t)(n0 + r) * Kd + k0 + tx] = f2bf(tile[tx][r]);
}

// ---------------- bf16 MFMA GEMM: C(MxN f32) = A(MxK) * Bt(NxK)^T + bias ----------------
#define BM 128
#define BN 128
#define BKT 64

__global__ __launch_bounds__(256) void gemm_bf16_kernel(
    const unsigned short* __restrict__ A,   // M x K bf16
    const unsigned short* __restrict__ Bt,  // N x K bf16 (pre-transposed)
    const float* __restrict__ bias,         // N
    float* __restrict__ C,                  // M x N f32
    int M, int N, int K)
{
    __shared__ __align__(16) unsigned short As[BM * BKT];  // swizzled [row][k], 128B rows
    __shared__ __align__(16) unsigned short Bs[BN * BKT];
    const int tid = threadIdx.x;
    const int lane = tid & 63;
    const int wid = tid >> 6;           // 0..3
    const int wm = wid >> 1, wn = wid & 1;
    const int bm = blockIdx.x, bn = blockIdx.y;
    const int lm = lane & 15;
    const int kb = lane >> 4;           // 0..3

    f32x4_t acc[4][4];
    #pragma unroll
    for (int i = 0; i < 4; ++i)
        #pragma unroll
        for (int j = 0; j < 4; ++j)
            acc[i][j] = f32x4_t{0.f, 0.f, 0.f, 0.f};

    for (int k0 = 0; k0 < K; k0 += BKT) {
        // stage A and B tiles: each wave issues 4x 1KB for each of A/B.
        // LDS linear dest (HW adds lane*16); global source pre-swizzled:
        // slot16 holds k-chunk (slot16 ^ (row&7))  [T2 / G4, rule 21]
        #pragma unroll
        for (int is = 0; is < 4; ++is) {
            int s = ((wid * 4 + is) << 10) + (lane << 4);     // byte slot in tile
            int row = s >> 7;                                  // 0..127
            int cc = ((s >> 4) & 7) ^ (row & 7);               // unswizzled k-chunk
            const unsigned short* ga = A + (size_t)(bm * BM + row) * K + k0 + cc * 8;
            __builtin_amdgcn_global_load_lds(
                (const __attribute__((address_space(1))) void*)ga,
                (__attribute__((address_space(3))) void*)((char*)As + ((wid * 4 + is) << 10)),
                16, 0, 0);
            const unsigned short* gb = Bt + (size_t)(bn * BN + row) * K + k0 + cc * 8;
            __builtin_amdgcn_global_load_lds(
                (const __attribute__((address_space(1))) void*)gb,
                (__attribute__((address_space(3))) void*)((char*)Bs + ((wid * 4 + is) << 10)),
                16, 0, 0);
        }
        __syncthreads();   // emits vmcnt(0) drain + barrier

        #pragma unroll
        for (int ks = 0; ks < 2; ++ks) {
            bf16x8_t af[4], bfr[4];
            #pragma unroll
            for (int i = 0; i < 4; ++i) {
                int row = wm * 64 + i * 16 + lm;
                int cc = (ks * 4 + kb) ^ (row & 7);
                af[i] = *(const bf16x8_t*)((const char*)As + row * 128 + cc * 16);
            }
            #pragma unroll
            for (int j = 0; j < 4; ++j) {
                int row = wn * 64 + j * 16 + lm;
                int cc = (ks * 4 + kb) ^ (row & 7);
                bfr[j] = *(const bf16x8_t*)((const char*)Bs + row * 128 + cc * 16);
            }
            #pragma unroll
            for (int i = 0; i < 4; ++i)
                #pragma unroll
                for (int j = 0; j < 4; ++j)
                    acc[i][j] = __builtin_amdgcn_mfma_f32_16x16x32_bf16(af[i], bfr[j], acc[i][j], 0, 0, 0);
        }
        __syncthreads();
    }

    // epilogue: C/D layout col=lane&15, row=(lane>>4)*4+reg  [m89]
    #pragma unroll
    for (int i = 0; i < 4; ++i) {
        int row = bm * BM + wm * 64 + i * 16 + (lane >> 4) * 4;
        #pragma unroll
        for (int j = 0; j < 4; ++j) {
            int col = bn * BN + wn * 64 + j * 16 + lm;
            float bv = bias[col];
            #pragma unroll
            for (int r = 0; r < 4; ++r)
                C[(size_t)(row + r) * N + col] = acc[i][j][r] + bv;
        }
    }
}

// ---------------- chunk-local cumsum along L (in place) + chunk sums ----------------
__global__ void cumsum_local_kernel(float* __restrict__ Qp, float* __restrict__ Kp,
                                    float* __restrict__ partQ, float* __restrict__ partK)
{
    int d = blockIdx.x * 256 + threadIdx.x;
    int c = blockIdx.y;
    int bz = blockIdx.z;
    int b = bz >> 1;
    float* buf = (bz & 1) ? Kp : Qp;
    float* part = (bz & 1) ? partK : partQ;
    size_t base = ((size_t)b * LSEQ + (size_t)c * CHUNK) * DMODEL + d;
    float run = 0.f;
    #pragma unroll 8
    for (int i = 0; i < CHUNK; ++i) {
        float v = buf[base + (size_t)i * DMODEL];
        run += v;
        buf[base + (size_t)i * DMODEL] = run;
    }
    part[((size_t)b * NCHUNK + c) * DMODEL + d] = run;
}

// ---------------- exclusive scan of chunk sums (in place) ----------------
__global__ void chunk_offsets_kernel(float* __restrict__ partQ, float* __restrict__ partK)
{
    int t = blockIdx.x * 256 + threadIdx.x;   // 0..4095  -> (b,d)
    float* part = blockIdx.y ? partK : partQ;
    int b = t >> 10, d = t & 1023;
    float run = 0.f;
    #pragma unroll
    for (int c = 0; c < NCHUNK; ++c) {
        size_t idx = ((size_t)b * NCHUNK + c) * DMODEL + d;
        float v = part[idx];
        part[idx] = run;
        run += v;
    }
}

// ---------------- fused normalize + low-rank scores + Wc mix ----------------
__device__ __forceinline__ void process_tensor(
    const float* __restrict__ S, const float* __restrict__ off,
    const float* __restrict__ Wp, float (&acc)[RDIM], float& n2,
    float (*tile)[33], int lane, int b, int h, int l0, int c)
{
    const int rlane = lane >> 3;
    const int c4 = (lane & 7) << 2;
    #pragma unroll
    for (int half = 0; half < 2; ++half) {
        const float4 ofv = *(const float4*)(off + ((size_t)b * NCHUNK + c) * DMODEL + h * 64 + half * 32 + c4);
        #pragma unroll
        for (int it = 0; it < 8; ++it) {
            int row = it * 8 + rlane;
            const float4 v = *(const float4*)(S + ((size_t)(b * LSEQ + l0 + row)) * DMODEL + h * 64 + half * 32 + c4);
            tile[row][c4 + 0] = v.x + ofv.x;
            tile[row][c4 + 1] = v.y + ofv.y;
            tile[row][c4 + 2] = v.z + ofv.z;
            tile[row][c4 + 3] = v.w + ofv.w;
        }
        asm volatile("s_waitcnt lgkmcnt(0)" ::: "memory");   // wave-internal LDS hazard fence
        const float* WpH = Wp + ((size_t)(h * DKH) + half * 32) * RDIM;  // We[h][dk][r]
        #pragma unroll 2
        for (int dk = 0; dk < 32; ++dk) {
            float x = tile[lane][dk];
            n2 = fmaf(x, x, n2);
            const float* wrow = WpH + dk * RDIM;             // wave-uniform -> s_load
            #pragma unroll
            for (int r = 0; r < RDIM; ++r)
                acc[r] = fmaf(x, wrow[r], acc[r]);
        }
    }
}

__global__ __launch_bounds__(64) void score_kernel(
    const float* __restrict__ Sq, const float* __restrict__ Sk,
    const float* __restrict__ offQ, const float* __restrict__ offK,
    const float* __restrict__ We, const float* __restrict__ Wr,
    const float* __restrict__ Wc, const float* __restrict__ bc,
    float* __restrict__ escore, float* __restrict__ rscore,
    unsigned short* __restrict__ out1)
{
    __shared__ float tile[64][33];
    const int lane = threadIdx.x;
    const int bh = blockIdx.y;
    const int b = bh >> 4, h = bh & 15;
    const int l0 = blockIdx.x * 64;
    const int c = l0 >> 8;               // chunk index (CHUNK=256)
    const int l = l0 + lane;

    float esc[RDIM], rsc[RDIM];
    #pragma unroll
    for (int r = 0; r < RDIM; ++r) { esc[r] = 0.f; rsc[r] = 0.f; }
    float nq2 = 0.f, nk2 = 0.f;

    process_tensor(Sq, offQ, We, esc, nq2, tile, lane, b, h, l0, c);
    process_tensor(Sk, offK, Wr, rsc, nk2, tile, lane, b, h, l0, c);

    // /(l+1) cancels under l2norm; exact guard: max(||S||, EPS*(l+1))
    float invq = 1.f / fmaxf(sqrtf(nq2), 1e-12f * (float)(l + 1));
    float invk = 1.f / fmaxf(sqrtf(nk2), 1e-12f * (float)(l + 1));
    #pragma unroll
    for (int r = 0; r < RDIM; ++r) { esc[r] *= invq; rsc[r] *= invk; }

    size_t ebase = (((size_t)(b * NHEAD + h)) * LSEQ + l) * RDIM;
    #pragma unroll
    for (int r = 0; r < RDIM; r += 2) {
        *(float2*)(escore + ebase + r) = make_float2(esc[r], esc[r + 1]);
        *(float2*)(rscore + ebase + r) = make_float2(rsc[r], rsc[r + 1]);
    }

    // out1[b,l,h*64+dk] = bc[dk] + sum_r esc*Wc[r][dk] + rsc*Wc[R+r][dk]  (bf16)
    size_t obase = ((size_t)(b * LSEQ + l)) * DMODEL + h * 64;
    for (int dk0 = 0; dk0 < DKH; dk0 += 4) {
        float o[4];
        #pragma unroll
        for (int q = 0; q < 4; ++q) {
            int dk = dk0 + q;
            float a = bc[dk];
            #pragma unroll
            for (int r = 0; r < RDIM; ++r) a = fmaf(esc[r], Wc[r * DKH + dk], a);
            #pragma unroll
            for (int r = 0; r < RDIM; ++r) a = fmaf(rsc[r], Wc[(RDIM + r) * DKH + dk], a);
            o[q] = a;
        }
        ushort4 pk;
        pk.x = f2bf(o[0]); pk.y = f2bf(o[1]); pk.z = f2bf(o[2]); pk.w = f2bf(o[3]);
        *(ushort4*)(out1 + obase + dk0) = pk;
    }
}

// ---------------- host launcher ----------------
extern "C" void kernel_launch(void* const* d_in, const int* in_sizes, int n_in,
                              void* d_out, int out_size, void* d_ws, size_t ws_size,
                              hipStream_t stream)
{
    const float* queries = (const float*)d_in[0];
    const float* keys    = (const float*)d_in[1];
    const float* Wq = (const float*)d_in[3];
    const float* bq = (const float*)d_in[4];
    const float* Wk = (const float*)d_in[5];
    const float* bk = (const float*)d_in[6];
    const float* We = (const float*)d_in[7];
    const float* Wr = (const float*)d_in[8];
    const float* Lam = (const float*)d_in[9];
    const float* Wc = (const float*)d_in[10];
    const float* bc = (const float*)d_in[11];
    const float* Wo = (const float*)d_in[12];
    const float* bo = (const float*)d_in[13];

    float* out = (float*)d_out;                        // [B,L,D]
    float* escore = out + (size_t)16777216;            // [B,H,L,R]
    float* rscore = out + (size_t)24641536;            // [B,H,L,R]
    float* lam_out = out + (size_t)32505856;           // [H,R]

    char* ws = (char*)d_ws;
    float* Qp = (float*)ws;                                    // 64 MiB f32 [B,L,D]
    float* Kp = (float*)(ws + 67108864);                       // 64 MiB
    unsigned short* qbf = (unsigned short*)(ws + 134217728);   // 32 MiB bf16 (q_bf / k_bf / out1 reuse)
    unsigned short* WqT = (unsigned short*)(ws + 167772160);   // 2 MiB bf16 (N,K)
    unsigned short* WkT = (unsigned short*)(ws + 169869312);
    unsigned short* WoT = (unsigned short*)(ws + 171966464);
    float* partQ = (float*)(ws + 174063616);                   // [B][NCHUNK][D]
    float* partK = (float*)(ws + 174325760);
    // total ws use: 174,587,904 bytes

    const int NELEM4 = 16777216 / 4;

    dim3 tb(32, 8);
    transpose_cvt_kernel<<<dim3(32, 32), tb, 0, stream>>>(Wq, WqT, DMODEL, DMODEL);
    transpose_cvt_kernel<<<dim3(32, 32), tb, 0, stream>>>(Wk, WkT, DMODEL, DMODEL);
    transpose_cvt_kernel<<<dim3(32, 32), tb, 0, stream>>>(Wo, WoT, DMODEL, DMODEL);

    cvt_bf16_kernel<<<2048, 256, 0, stream>>>(queries, qbf, NELEM4);
    gemm_bf16_kernel<<<dim3(128, 8), 256, 0, stream>>>(qbf, WqT, bq, Qp, 16384, 1024, 1024);
    cvt_bf16_kernel<<<2048, 256, 0, stream>>>(keys, qbf, NELEM4);
    gemm_bf16_kernel<<<dim3(128, 8), 256, 0, stream>>>(qbf, WkT, bk, Kp, 16384, 1024, 1024);

    cumsum_local_kernel<<<dim3(4, NCHUNK, 8), 256, 0, stream>>>(Qp, Kp, partQ, partK);
    chunk_offsets_kernel<<<dim3(16, 2), 256, 0, stream>>>(partQ, partK);

    score_kernel<<<dim3(64, 64), 64, 0, stream>>>(Qp, Kp, partQ, partK, We, Wr, Wc, bc,
                                                  escore, rscore, qbf);

    gemm_bf16_kernel<<<dim3(128, 8), 256, 0, stream>>>(qbf, WoT, bo, out, 16384, 1024, 1024);

    hipMemcpyAsync(lam_out, Lam, 480 * sizeof(float), hipMemcpyDeviceToDevice, stream);
}

// Round 2
// 385.001 us; speedup vs baseline: 1.2326x; 1.2326x over previous
//
#include <hip/hip_runtime.h>
#include <hip/hip_bf16.h>

#define BATCH 4
#define LSEQ 4096
#define DMODEL 1024
#define NHEAD 16
#define RDIM 30
#define DKH 64
#define NCHUNK 32
#define CHUNK 128

typedef __attribute__((ext_vector_type(8))) short bf16x8_t;
typedef __attribute__((ext_vector_type(4))) float f32x4_t;

static __device__ __forceinline__ unsigned short f2bf(float f) {
    __hip_bfloat16 h = __float2bfloat16(f);
    unsigned short u;
    __builtin_memcpy(&u, &h, 2);
    return u;
}
static __device__ __forceinline__ float b2f(unsigned short u) {
    unsigned v = ((unsigned)u) << 16;
    float f;
    __builtin_memcpy(&f, &v, 4);
    return f;
}

// ---------------- convert f32 -> bf16 (vectorized) ----------------
__global__ void cvt_bf16_kernel(const float* __restrict__ in, unsigned short* __restrict__ out, int n4) {
    int i = blockIdx.x * blockDim.x + threadIdx.x;
    int stride = gridDim.x * blockDim.x;
    for (; i < n4; i += stride) {
        float4 v = ((const float4*)in)[i];
        ushort4 o;
        o.x = f2bf(v.x); o.y = f2bf(v.y); o.z = f2bf(v.z); o.w = f2bf(v.w);
        ((ushort4*)out)[i] = o;
    }
}

// ---------------- transpose + convert: W (K,N) f32 -> Wt (N,K) bf16 ----------------
__global__ void transpose_cvt_kernel(const float* __restrict__ W, unsigned short* __restrict__ outT,
                                     int Kd, int Nd) {
    __shared__ float tile[32][33];
    int n0 = blockIdx.x * 32, k0 = blockIdx.y * 32;
    int tx = threadIdx.x, ty = threadIdx.y;
    #pragma unroll
    for (int r = ty; r < 32; r += 8)
        tile[r][tx] = W[(size_t)(k0 + r) * Nd + n0 + tx];
    __syncthreads();
    #pragma unroll
    for (int r = ty; r < 32; r += 8)
        outT[(size_t)(n0 + r) * Kd + k0 + tx] = f2bf(tile[tx][r]);
}

// ---------------- WfoldT[n][h*64+j] = sum_dk Wc[jr][dk] * Wo[h*64+dk][n]  (bf16) ----------------
// j<30 -> jr=j ; 32<=j<62 -> jr=j-2 ; else 0-pad.
__global__ __launch_bounds__(256) void wfold_kernel(
    const float* __restrict__ Wc, const float* __restrict__ Wo,
    unsigned short* __restrict__ WfoldT)
{
    __shared__ float WoT[64][65];  // [dk][n]
    __shared__ float WcT[64][61];  // [dk][jr]
    const int tid = threadIdx.x;
    const int n0 = blockIdx.x * 64, h = blockIdx.y;
    for (int i = tid; i < 4096; i += 256) {
        int dk = i >> 6, n = i & 63;
        WoT[dk][n] = Wo[(size_t)(h * 64 + dk) * DMODEL + n0 + n];
    }
    for (int i = tid; i < 3840; i += 256) {
        int j = i >> 6, dk = i & 63;
        WcT[dk][j] = Wc[j * 64 + dk];
    }
    __syncthreads();
    #pragma unroll 1
    for (int oo = 0; oo < 16; ++oo) {
        int n = (tid >> 6) + oo * 4;
        int j = tid & 63;
        int jr = (j < 30) ? j : (j >= 32 && j < 62) ? (j - 2) : -1;
        float acc = 0.f;
        if (jr >= 0) {
            #pragma unroll
            for (int dk = 0; dk < 64; ++dk)
                acc = fmaf(WcT[dk][jr], WoT[dk][n], acc);
        }
        WfoldT[(size_t)(n0 + n) * 1024 + h * 64 + j] = f2bf(acc);
    }
}

// ---------------- bias2[n] = bo[n] + sum_d bc[d&63]*Wo[d][n] ----------------
__global__ void bias2_kernel(const float* __restrict__ Wo, const float* __restrict__ bc,
                             const float* __restrict__ bo, float* __restrict__ bias2) {
    int n = blockIdx.x * 256 + threadIdx.x;
    float a = bo[n];
    for (int d = 0; d < DMODEL; ++d)
        a = fmaf(bc[d & 63], Wo[(size_t)d * DMODEL + n], a);
    bias2[n] = a;
}

// ---------------- bf16 MFMA GEMM: C(MxN) = A(MxK) * Bt(NxK)^T + bias ----------------
#define BM 128
#define BN 128
#define BKT 64

template <bool BF16_OUT>
__global__ __launch_bounds__(256) void gemm_bf16_kernel(
    const unsigned short* __restrict__ A,   // M x K bf16
    const unsigned short* __restrict__ Bt,  // N x K bf16 (pre-transposed)
    const float* __restrict__ bias,         // N
    void* __restrict__ Cv,                  // M x N (f32 or bf16)
    int M, int N, int K)
{
    __shared__ __align__(16) unsigned short As[BM * BKT];
    __shared__ __align__(16) unsigned short Bs[BN * BKT];
    const int tid = threadIdx.x;
    const int lane = tid & 63;
    const int wid = tid >> 6;
    const int wm = wid >> 1, wn = wid & 1;
    const int bm = blockIdx.x, bn = blockIdx.y;
    const int lm = lane & 15;
    const int kb = lane >> 4;

    f32x4_t acc[4][4];
    #pragma unroll
    for (int i = 0; i < 4; ++i)
        #pragma unroll
        for (int j = 0; j < 4; ++j)
            acc[i][j] = f32x4_t{0.f, 0.f, 0.f, 0.f};

    for (int k0 = 0; k0 < K; k0 += BKT) {
        #pragma unroll
        for (int is = 0; is < 4; ++is) {
            int s = ((wid * 4 + is) << 10) + (lane << 4);
            int row = s >> 7;
            int cc = ((s >> 4) & 7) ^ (row & 7);     // T2 swizzle: pre-swizzled source, linear dest
            const unsigned short* ga = A + (size_t)(bm * BM + row) * K + k0 + cc * 8;
            __builtin_amdgcn_global_load_lds(
                (const __attribute__((address_space(1))) void*)ga,
                (__attribute__((address_space(3))) void*)((char*)As + ((wid * 4 + is) << 10)),
                16, 0, 0);
            const unsigned short* gb = Bt + (size_t)(bn * BN + row) * K + k0 + cc * 8;
            __builtin_amdgcn_global_load_lds(
                (const __attribute__((address_space(1))) void*)gb,
                (__attribute__((address_space(3))) void*)((char*)Bs + ((wid * 4 + is) << 10)),
                16, 0, 0);
        }
        __syncthreads();

        #pragma unroll
        for (int ks = 0; ks < 2; ++ks) {
            bf16x8_t af[4], bfr[4];
            #pragma unroll
            for (int i = 0; i < 4; ++i) {
                int row = wm * 64 + i * 16 + lm;
                int cc = (ks * 4 + kb) ^ (row & 7);
                af[i] = *(const bf16x8_t*)((const char*)As + row * 128 + cc * 16);
            }
            #pragma unroll
            for (int j = 0; j < 4; ++j) {
                int row = wn * 64 + j * 16 + lm;
                int cc = (ks * 4 + kb) ^ (row & 7);
                bfr[j] = *(const bf16x8_t*)((const char*)Bs + row * 128 + cc * 16);
            }
            #pragma unroll
            for (int i = 0; i < 4; ++i)
                #pragma unroll
                for (int j = 0; j < 4; ++j)
                    acc[i][j] = __builtin_amdgcn_mfma_f32_16x16x32_bf16(af[i], bfr[j], acc[i][j], 0, 0, 0);
        }
        __syncthreads();
    }

    #pragma unroll
    for (int i = 0; i < 4; ++i) {
        int row = bm * BM + wm * 64 + i * 16 + (lane >> 4) * 4;
        #pragma unroll
        for (int j = 0; j < 4; ++j) {
            int col = bn * BN + wn * 64 + j * 16 + lm;
            float bv = bias[col];
            #pragma unroll
            for (int r = 0; r < 4; ++r) {
                float v = acc[i][j][r] + bv;
                if constexpr (BF16_OUT)
                    ((unsigned short*)Cv)[(size_t)(row + r) * N + col] = f2bf(v);
                else
                    ((float*)Cv)[(size_t)(row + r) * N + col] = v;
            }
        }
    }
}

// ---------------- chunk-local cumsum along L, bf16 in/out, f32 partials ----------------
__global__ __launch_bounds__(256) void cumsum_local_kernel(
    unsigned short* __restrict__ Qb, unsigned short* __restrict__ Kb,
    float* __restrict__ partQ, float* __restrict__ partK)
{
    const int tid = threadIdx.x;           // d4 = tid*4
    const int c = blockIdx.x;              // 0..31
    const int bz = blockIdx.y;             // 0..7
    const int b = bz >> 1;
    unsigned short* buf = (bz & 1) ? Kb : Qb;
    float* part = (bz & 1) ? partK : partQ;
    size_t base = ((size_t)(b * LSEQ + c * CHUNK)) * DMODEL + tid * 4;
    float rx = 0.f, ry = 0.f, rz = 0.f, rw = 0.f;
    #pragma unroll 4
    for (int i = 0; i < CHUNK; ++i) {
        ushort4 v = *(ushort4*)(buf + base + (size_t)i * DMODEL);
        rx += b2f(v.x); ry += b2f(v.y); rz += b2f(v.z); rw += b2f(v.w);
        ushort4 o;
        o.x = f2bf(rx); o.y = f2bf(ry); o.z = f2bf(rz); o.w = f2bf(rw);
        *(ushort4*)(buf + base + (size_t)i * DMODEL) = o;
    }
    float4 p = make_float4(rx, ry, rz, rw);
    *(float4*)(part + ((size_t)(b * NCHUNK + c)) * DMODEL + tid * 4) = p;
}

// ---------------- exclusive scan of chunk sums (in place) ----------------
__global__ void chunk_offsets_kernel(float* __restrict__ partQ, float* __restrict__ partK)
{
    int t = blockIdx.x * 256 + threadIdx.x;   // 0..4095 -> (b,d)
    float* part = blockIdx.y ? partK : partQ;
    int b = t >> 10, d = t & 1023;
    float run = 0.f;
    #pragma unroll
    for (int c = 0; c < NCHUNK; ++c) {
        size_t idx = ((size_t)(b * NCHUNK + c)) * DMODEL + d;
        float v = part[idx];
        part[idx] = run;
        run += v;
    }
}

// ---------------- fused normalize + low-rank scores ----------------
__device__ __forceinline__ float proc_tensor(
    const unsigned short* __restrict__ rowp,  // lane's row, 64 bf16
    const float* __restrict__ off,            // 64 f32 chunk offsets (wave-uniform)
    const float* __restrict__ W,              // We[h] : [64][30] f32 (wave-uniform)
    float (&sc)[RDIM])
{
    bf16x8_t pk[8];
    #pragma unroll
    for (int i = 0; i < 8; ++i) pk[i] = ((const bf16x8_t*)rowp)[i];
    #pragma unroll
    for (int r = 0; r < RDIM; ++r) sc[r] = 0.f;
    float n2 = 0.f;
    #pragma unroll
    for (int dk = 0; dk < 64; ++dk) {
        float x = b2f((unsigned short)pk[dk >> 3][dk & 7]) + off[dk];
        n2 = fmaf(x, x, n2);
        const float* wrow = W + dk * RDIM;    // wave-uniform -> s_load
        #pragma unroll
        for (int r = 0; r < RDIM; ++r) sc[r] = fmaf(x, wrow[r], sc[r]);
    }
    return n2;
}

__global__ __launch_bounds__(256) void score_kernel(
    const unsigned short* __restrict__ Qc, const unsigned short* __restrict__ Kc,
    const float* __restrict__ partQ, const float* __restrict__ partK,
    const float* __restrict__ We, const float* __restrict__ Wr,
    float* __restrict__ escore, float* __restrict__ rscore,
    unsigned short* __restrict__ sbf)
{
    const int tid = threadIdx.x;
    const int lane = tid & 63;
    const int w = tid >> 6;
    const int c = blockIdx.x;                 // 256-row macro block
    const int bh = blockIdx.y;
    const int b = bh >> 4, h = bh & 15;
    const int l = c * 256 + w * 64 + lane;
    const int co = l >> 7;                    // 128-row offset chunk (wave-uniform)

    float sc[RDIM];

    // ---- Q ----
    {
        const unsigned short* rowp = Qc + ((size_t)(b * LSEQ + l)) * DMODEL + h * 64;
        const float* off = partQ + ((size_t)(b * NCHUNK + co)) * DMODEL + h * 64;
        float n2 = proc_tensor(rowp, off, We + (size_t)h * 64 * RDIM, sc);
        float inv = 1.f / fmaxf(sqrtf(n2), 1e-12f * (float)(l + 1));
        #pragma unroll
        for (int r = 0; r < RDIM; ++r) sc[r] *= inv;
        size_t ebase = (((size_t)(b * NHEAD + h)) * LSEQ + l) * RDIM;
        #pragma unroll
        for (int r = 0; r < RDIM; r += 2)
            *(float2*)(escore + ebase + r) = make_float2(sc[r], sc[r + 1]);
        size_t sbase = ((size_t)(b * LSEQ + l)) * 1024 + h * 64;
        #pragma unroll
        for (int g = 0; g < 4; ++g) {
            bf16x8_t o;
            #pragma unroll
            for (int e = 0; e < 8; ++e) {
                int idx = g * 8 + e;
                o[e] = (idx < RDIM) ? (short)f2bf(sc[idx]) : (short)0;
            }
            ((bf16x8_t*)(sbf + sbase))[g] = o;
        }
    }
    // ---- K ----
    {
        const unsigned short* rowp = Kc + ((size_t)(b * LSEQ + l)) * DMODEL + h * 64;
        const float* off = partK + ((size_t)(b * NCHUNK + co)) * DMODEL + h * 64;
        float n2 = proc_tensor(rowp, off, Wr + (size_t)h * 64 * RDIM, sc);
        float inv = 1.f / fmaxf(sqrtf(n2), 1e-12f * (float)(l + 1));
        #pragma unroll
        for (int r = 0; r < RDIM; ++r) sc[r] *= inv;
        size_t ebase = (((size_t)(b * NHEAD + h)) * LSEQ + l) * RDIM;
        #pragma unroll
        for (int r = 0; r < RDIM; r += 2)
            *(float2*)(rscore + ebase + r) = make_float2(sc[r], sc[r + 1]);
        size_t sbase = ((size_t)(b * LSEQ + l)) * 1024 + h * 64 + 32;
        #pragma unroll
        for (int g = 0; g < 4; ++g) {
            bf16x8_t o;
            #pragma unroll
            for (int e = 0; e < 8; ++e) {
                int idx = g * 8 + e;
                o[e] = (idx < RDIM) ? (short)f2bf(sc[idx]) : (short)0;
            }
            ((bf16x8_t*)(sbf + sbase))[g] = o;
        }
    }
}

// ---------------- host launcher ----------------
extern "C" void kernel_launch(void* const* d_in, const int* in_sizes, int n_in,
                              void* d_out, int out_size, void* d_ws, size_t ws_size,
                              hipStream_t stream)
{
    const float* queries = (const float*)d_in[0];
    const float* keys    = (const float*)d_in[1];
    const float* Wq = (const float*)d_in[3];
    const float* bq = (const float*)d_in[4];
    const float* Wk = (const float*)d_in[5];
    const float* bk = (const float*)d_in[6];
    const float* We = (const float*)d_in[7];
    const float* Wr = (const float*)d_in[8];
    const float* Lam = (const float*)d_in[9];
    const float* Wc = (const float*)d_in[10];
    const float* bc = (const float*)d_in[11];
    const float* Wo = (const float*)d_in[12];
    const float* bo = (const float*)d_in[13];

    float* out = (float*)d_out;                        // [B,L,D]
    float* escore = out + (size_t)16777216;            // [B,H,L,R]
    float* rscore = out + (size_t)24641536;            // [B,H,L,R]
    float* lam_out = out + (size_t)32505856;           // [H,R]

    char* ws = (char*)d_ws;
    unsigned short* Qb  = (unsigned short*)ws;                    // 32 MiB bf16 [B,L,D]
    unsigned short* Kb  = (unsigned short*)(ws + 33554432);       // 32 MiB
    unsigned short* abf = (unsigned short*)(ws + 67108864);       // 32 MiB (A-staging / score_bf)
    unsigned short* WqT = (unsigned short*)(ws + 100663296);      // 2 MiB
    unsigned short* WkT = (unsigned short*)(ws + 102760448);      // 2 MiB
    unsigned short* WfT = (unsigned short*)(ws + 104857600);      // 2 MiB
    float* bias2 = (float*)(ws + 106954752);                      // 4 KiB
    float* partQ = (float*)(ws + 106958848);                      // [4][32][1024] f32 = 512 KiB
    float* partK = (float*)(ws + 107483136);
    // total ws use: ~108 MiB

    const int NELEM4 = 16777216 / 4;

    dim3 tb(32, 8);
    transpose_cvt_kernel<<<dim3(32, 32), tb, 0, stream>>>(Wq, WqT, DMODEL, DMODEL);
    transpose_cvt_kernel<<<dim3(32, 32), tb, 0, stream>>>(Wk, WkT, DMODEL, DMODEL);
    wfold_kernel<<<dim3(16, 16), 256, 0, stream>>>(Wc, Wo, WfT);
    bias2_kernel<<<4, 256, 0, stream>>>(Wo, bc, bo, bias2);

    cvt_bf16_kernel<<<2048, 256, 0, stream>>>(queries, abf, NELEM4);
    gemm_bf16_kernel<true><<<dim3(128, 8), 256, 0, stream>>>(abf, WqT, bq, Qb, 16384, 1024, 1024);
    cvt_bf16_kernel<<<2048, 256, 0, stream>>>(keys, abf, NELEM4);
    gemm_bf16_kernel<true><<<dim3(128, 8), 256, 0, stream>>>(abf, WkT, bk, Kb, 16384, 1024, 1024);

    cumsum_local_kernel<<<dim3(NCHUNK, 8), 256, 0, stream>>>(Qb, Kb, partQ, partK);
    chunk_offsets_kernel<<<dim3(16, 2), 256, 0, stream>>>(partQ, partK);

    score_kernel<<<dim3(16, 64), 256, 0, stream>>>(Qb, Kb, partQ, partK, We, Wr,
                                                   escore, rscore, abf);

    gemm_bf16_kernel<false><<<dim3(128, 8), 256, 0, stream>>>(abf, WfT, bias2, out, 16384, 1024, 1024);

    hipMemcpyAsync(lam_out, Lam, 480 * sizeof(float), hipMemcpyDeviceToDevice, stream);
}

// Round 3
// 323.447 us; speedup vs baseline: 1.4672x; 1.1903x over previous
//
#include <hip/hip_runtime.h>
#include <hip/hip_bf16.h>

#define BATCH 4
#define LSEQ 4096
#define DMODEL 1024
#define NHEAD 16
#define RDIM 30
#define DKH 64
#define NCHUNK 32
#define CHUNK 128

typedef __attribute__((ext_vector_type(8))) short bf16x8_t;
typedef __attribute__((ext_vector_type(4))) float f32x4_t;

static __device__ __forceinline__ unsigned short f2bf(float f) {
    __hip_bfloat16 h = __float2bfloat16(f);
    unsigned short u;
    __builtin_memcpy(&u, &h, 2);
    return u;
}
static __device__ __forceinline__ float b2f(unsigned short u) {
    unsigned v = ((unsigned)u) << 16;
    float f;
    __builtin_memcpy(&f, &v, 4);
    return f;
}

// ---------------- transpose + convert: W (K,N) f32 -> Wt (N,K) bf16 ----------------
__global__ void transpose_cvt_kernel(const float* __restrict__ W, unsigned short* __restrict__ outT,
                                     int Kd, int Nd) {
    __shared__ float tile[32][33];
    int n0 = blockIdx.x * 32, k0 = blockIdx.y * 32;
    int tx = threadIdx.x, ty = threadIdx.y;
    #pragma unroll
    for (int r = ty; r < 32; r += 8)
        tile[r][tx] = W[(size_t)(k0 + r) * Nd + n0 + tx];
    __syncthreads();
    #pragma unroll
    for (int r = ty; r < 32; r += 8)
        outT[(size_t)(n0 + r) * Kd + k0 + tx] = f2bf(tile[tx][r]);
}

// ---------------- pack We/Wr [H][64][30] f32 -> WP [H][32 cols][64 k] bf16 (col-major) ----------------
__global__ void wpack_kernel(const float* __restrict__ We, const float* __restrict__ Wr,
                             unsigned short* __restrict__ WeP, unsigned short* __restrict__ WrP) {
    int h = blockIdx.x;
    const float* W = blockIdx.y ? Wr : We;
    unsigned short* O = blockIdx.y ? WrP : WeP;
    for (int idx = threadIdx.x; idx < 2048; idx += 256) {
        int col = idx >> 6, k = idx & 63;
        float v = (col < RDIM) ? W[((size_t)h * 64 + k) * RDIM + col] : 0.f;
        O[((size_t)h << 11) + idx] = f2bf(v);
    }
}

// ---------------- WfoldT[n][h*64+j] = sum_dk Wc[jr][dk] * Wo[h*64+dk][n]  (bf16) ----------------
__global__ __launch_bounds__(256) void wfold_kernel(
    const float* __restrict__ Wc, const float* __restrict__ Wo,
    unsigned short* __restrict__ WfoldT)
{
    __shared__ float WoT[64][65];
    __shared__ float WcT[64][61];
    const int tid = threadIdx.x;
    const int n0 = blockIdx.x * 64, h = blockIdx.y;
    for (int i = tid; i < 4096; i += 256) {
        int dk = i >> 6, n = i & 63;
        WoT[dk][n] = Wo[(size_t)(h * 64 + dk) * DMODEL + n0 + n];
    }
    for (int i = tid; i < 3840; i += 256) {
        int j = i >> 6, dk = i & 63;
        WcT[dk][j] = Wc[j * 64 + dk];
    }
    __syncthreads();
    #pragma unroll 1
    for (int oo = 0; oo < 16; ++oo) {
        int n = (tid >> 6) + oo * 4;
        int j = tid & 63;
        int jr = (j < 30) ? j : (j >= 32 && j < 62) ? (j - 2) : -1;
        float acc = 0.f;
        if (jr >= 0) {
            #pragma unroll
            for (int dk = 0; dk < 64; ++dk)
                acc = fmaf(WcT[dk][jr], WoT[dk][n], acc);
        }
        WfoldT[(size_t)(n0 + n) * 1024 + h * 64 + j] = f2bf(acc);
    }
}

// ---------------- bias2[n] = bo[n] + sum_d bc[d&63]*Wo[d][n] ----------------
__global__ void bias2_kernel(const float* __restrict__ Wo, const float* __restrict__ bc,
                             const float* __restrict__ bo, float* __restrict__ bias2) {
    int n = blockIdx.x * 256 + threadIdx.x;
    float a = bo[n];
    for (int d = 0; d < DMODEL; ++d)
        a = fmaf(bc[d & 63], Wo[(size_t)d * DMODEL + n], a);
    bias2[n] = a;
}

// ---------------- bf16 MFMA GEMM: C(MxN) = A(MxK) * Bt(NxK)^T + bias ----------------
#define BM 128
#define BN 128
#define BKT 64

template <bool AF32, bool BF16_OUT>
__global__ __launch_bounds__(256) void gemm_kernel(
    const void* __restrict__ Av,            // M x K (f32 if AF32 else bf16)
    const unsigned short* __restrict__ Bt,  // N x K bf16 (pre-transposed)
    const float* __restrict__ bias,         // N
    void* __restrict__ Cv,                  // M x N (f32 or bf16)
    int M, int N, int K)
{
    __shared__ __align__(16) unsigned short As[BM * BKT];
    __shared__ __align__(16) unsigned short Bs[BN * BKT];
    const int tid = threadIdx.x;
    const int lane = tid & 63;
    const int wid = tid >> 6;
    const int wm = wid >> 1, wn = wid & 1;
    const int bm = blockIdx.x, bn = blockIdx.y;
    const int lm = lane & 15;
    const int kb = lane >> 4;

    f32x4_t acc[4][4];
    #pragma unroll
    for (int i = 0; i < 4; ++i)
        #pragma unroll
        for (int j = 0; j < 4; ++j)
            acc[i][j] = f32x4_t{0.f, 0.f, 0.f, 0.f};

    for (int k0 = 0; k0 < K; k0 += BKT) {
        #pragma unroll
        for (int is = 0; is < 4; ++is) {
            int s = ((wid * 4 + is) << 10) + (lane << 4);
            int row = s >> 7;
            int cc = ((s >> 4) & 7) ^ (row & 7);     // T2: pre-swizzled source, linear dest
            const unsigned short* gb = Bt + (size_t)(bn * BN + row) * K + k0 + cc * 8;
            __builtin_amdgcn_global_load_lds(
                (const __attribute__((address_space(1))) void*)gb,
                (__attribute__((address_space(3))) void*)((char*)Bs + ((wid * 4 + is) << 10)),
                16, 0, 0);
            if constexpr (!AF32) {
                const unsigned short* ga = (const unsigned short*)Av + (size_t)(bm * BM + row) * K + k0 + cc * 8;
                __builtin_amdgcn_global_load_lds(
                    (const __attribute__((address_space(1))) void*)ga,
                    (__attribute__((address_space(3))) void*)((char*)As + ((wid * 4 + is) << 10)),
                    16, 0, 0);
            }
        }
        if constexpr (AF32) {
            // reg-stage A: coalesced float4 loads, cvt, ds_write to the SAME swizzled slot
            const float* A32 = (const float*)Av;
            #pragma unroll
            for (int p = 0; p < 8; ++p) {
                int row = wid * 32 + p * 4 + (lane >> 4);
                int f4 = lane & 15;                     // f32 quad within row's 64 k
                const float4 v = *(const float4*)(A32 + (size_t)(bm * BM + row) * K + k0 + f4 * 4);
                ushort4 pk;
                pk.x = f2bf(v.x); pk.y = f2bf(v.y); pk.z = f2bf(v.z); pk.w = f2bf(v.w);
                int kc = f4 >> 1;
                char* dst = (char*)As + row * 128 + ((kc ^ (row & 7)) << 4) + (f4 & 1) * 8;
                *(ushort4*)dst = pk;
            }
        }
        __syncthreads();

        #pragma unroll
        for (int ks = 0; ks < 2; ++ks) {
            bf16x8_t af[4], bfr[4];
            #pragma unroll
            for (int i = 0; i < 4; ++i) {
                int row = wm * 64 + i * 16 + lm;
                int cc = (ks * 4 + kb) ^ (row & 7);
                af[i] = *(const bf16x8_t*)((const char*)As + row * 128 + cc * 16);
            }
            #pragma unroll
            for (int j = 0; j < 4; ++j) {
                int row = wn * 64 + j * 16 + lm;
                int cc = (ks * 4 + kb) ^ (row & 7);
                bfr[j] = *(const bf16x8_t*)((const char*)Bs + row * 128 + cc * 16);
            }
            #pragma unroll
            for (int i = 0; i < 4; ++i)
                #pragma unroll
                for (int j = 0; j < 4; ++j)
                    acc[i][j] = __builtin_amdgcn_mfma_f32_16x16x32_bf16(af[i], bfr[j], acc[i][j], 0, 0, 0);
        }
        __syncthreads();
    }

    #pragma unroll
    for (int i = 0; i < 4; ++i) {
        int row = bm * BM + wm * 64 + i * 16 + (lane >> 4) * 4;
        #pragma unroll
        for (int j = 0; j < 4; ++j) {
            int col = bn * BN + wn * 64 + j * 16 + lm;
            float bv = bias[col];
            #pragma unroll
            for (int r = 0; r < 4; ++r) {
                float v = acc[i][j][r] + bv;
                if constexpr (BF16_OUT)
                    ((unsigned short*)Cv)[(size_t)(row + r) * N + col] = f2bf(v);
                else
                    ((float*)Cv)[(size_t)(row + r) * N + col] = v;
            }
        }
    }
}

// ---------------- chunk-local cumsum along L, bf16 in/out, f32 partials ----------------
__global__ __launch_bounds__(256) void cumsum_local_kernel(
    unsigned short* __restrict__ Qb, unsigned short* __restrict__ Kb,
    float* __restrict__ partQ, float* __restrict__ partK)
{
    const int tid = threadIdx.x;
    const int c = blockIdx.x;
    const int bz = blockIdx.y;
    const int b = bz >> 1;
    unsigned short* buf = (bz & 1) ? Kb : Qb;
    float* part = (bz & 1) ? partK : partQ;
    size_t base = ((size_t)(b * LSEQ + c * CHUNK)) * DMODEL + tid * 4;
    float rx = 0.f, ry = 0.f, rz = 0.f, rw = 0.f;
    #pragma unroll 4
    for (int i = 0; i < CHUNK; ++i) {
        ushort4 v = *(ushort4*)(buf + base + (size_t)i * DMODEL);
        rx += b2f(v.x); ry += b2f(v.y); rz += b2f(v.z); rw += b2f(v.w);
        ushort4 o;
        o.x = f2bf(rx); o.y = f2bf(ry); o.z = f2bf(rz); o.w = f2bf(rw);
        *(ushort4*)(buf + base + (size_t)i * DMODEL) = o;
    }
    float4 p = make_float4(rx, ry, rz, rw);
    *(float4*)(part + ((size_t)(b * NCHUNK + c)) * DMODEL + tid * 4) = p;
}

// ---------------- exclusive scan of chunk sums (in place) ----------------
__global__ void chunk_offsets_kernel(float* __restrict__ partQ, float* __restrict__ partK)
{
    int t = blockIdx.x * 256 + threadIdx.x;
    float* part = blockIdx.y ? partK : partQ;
    int b = t >> 10, d = t & 1023;
    float run = 0.f;
    #pragma unroll
    for (int c = 0; c < NCHUNK; ++c) {
        size_t idx = ((size_t)(b * NCHUNK + c)) * DMODEL + d;
        float v = part[idx];
        part[idx] = run;
        run += v;
    }
}

// ---------------- MFMA score kernel: per wave, 64 rows x 32 cols, K=64 ----------------
__global__ __launch_bounds__(256) void score_kernel(
    const unsigned short* __restrict__ Qc, const unsigned short* __restrict__ Kc,
    const float* __restrict__ partQ, const float* __restrict__ partK,
    const unsigned short* __restrict__ WeP, const unsigned short* __restrict__ WrP,
    float* __restrict__ escore, float* __restrict__ rscore,
    unsigned short* __restrict__ sbf)
{
    __shared__ float n2buf[4][64];
    const int tid = threadIdx.x;
    const int lane = tid & 63;
    const int w = tid >> 6;
    const int lm = lane & 15;
    const int lk = lane >> 4;
    const int c = blockIdx.x;
    const int bh = blockIdx.y;
    const int z = blockIdx.z;                 // 0=Q,1=K
    const int b = bh >> 4, h = bh & 15;
    const unsigned short* X = z ? Kc : Qc;
    const float* part = z ? partK : partQ;
    const unsigned short* WP = z ? WrP : WeP;
    float* eout = z ? rscore : escore;
    const int row0 = c * 256 + w * 64;
    const int co = c * 2 + (w >> 1);          // 128-row chunk, wave-uniform

    // chunk offsets for this lane's k-slice (k = 32*ks + lk*8 + j)
    const float* offp = part + ((size_t)(b * NCHUNK + co)) * DMODEL + h * 64 + lk * 8;
    float o0[8], o1[8];
    {
        float4 a = *(const float4*)(offp);
        float4 bb = *(const float4*)(offp + 4);
        float4 cc = *(const float4*)(offp + 32);
        float4 dd = *(const float4*)(offp + 36);
        o0[0] = a.x; o0[1] = a.y; o0[2] = a.z; o0[3] = a.w;
        o0[4] = bb.x; o0[5] = bb.y; o0[6] = bb.z; o0[7] = bb.w;
        o1[0] = cc.x; o1[1] = cc.y; o1[2] = cc.z; o1[3] = cc.w;
        o1[4] = dd.x; o1[5] = dd.y; o1[6] = dd.z; o1[7] = dd.w;
    }

    // B fragments: WP[h][col][k]; col = 16j + lm, k = 32ks + lk*8
    const unsigned short* wpb = WP + ((size_t)h << 11) + lm * 64 + lk * 8;
    bf16x8_t b00 = *(const bf16x8_t*)(wpb);
    bf16x8_t b01 = *(const bf16x8_t*)(wpb + 32);
    bf16x8_t b10 = *(const bf16x8_t*)(wpb + 16 * 64);
    bf16x8_t b11 = *(const bf16x8_t*)(wpb + 16 * 64 + 32);

    f32x4_t acc[4][2];
    float n2p[4];
    #pragma unroll
    for (int i = 0; i < 4; ++i) {
        n2p[i] = 0.f;
        acc[i][0] = f32x4_t{0.f, 0.f, 0.f, 0.f};
        acc[i][1] = f32x4_t{0.f, 0.f, 0.f, 0.f};
    }

    const unsigned short* xbase = X + ((size_t)(b * LSEQ + row0 + lm)) * DMODEL + h * 64 + lk * 8;
    #pragma unroll
    for (int i = 0; i < 4; ++i) {
        const unsigned short* xp = xbase + (size_t)(16 * i) * DMODEL;
        bf16x8_t x0 = *(const bf16x8_t*)(xp);
        bf16x8_t x1 = *(const bf16x8_t*)(xp + 32);
        bf16x8_t xa0, xa1;
        #pragma unroll
        for (int j = 0; j < 8; ++j) {
            float xf = b2f((unsigned short)x0[j]) + o0[j];
            n2p[i] = fmaf(xf, xf, n2p[i]);
            xa0[j] = (short)f2bf(xf);
        }
        #pragma unroll
        for (int j = 0; j < 8; ++j) {
            float xf = b2f((unsigned short)x1[j]) + o1[j];
            n2p[i] = fmaf(xf, xf, n2p[i]);
            xa1[j] = (short)f2bf(xf);
        }
        acc[i][0] = __builtin_amdgcn_mfma_f32_16x16x32_bf16(xa0, b00, acc[i][0], 0, 0, 0);
        acc[i][1] = __builtin_amdgcn_mfma_f32_16x16x32_bf16(xa0, b10, acc[i][1], 0, 0, 0);
        acc[i][0] = __builtin_amdgcn_mfma_f32_16x16x32_bf16(xa1, b01, acc[i][0], 0, 0, 0);
        acc[i][1] = __builtin_amdgcn_mfma_f32_16x16x32_bf16(xa1, b11, acc[i][1], 0, 0, 0);
    }

    // full row norms: reduce over k-groups (lanes lk=0..3 hold partials of same row)
    #pragma unroll
    for (int i = 0; i < 4; ++i) {
        n2p[i] += __shfl_xor(n2p[i], 16);
        n2p[i] += __shfl_xor(n2p[i], 32);
    }
    if (lane < 16) {
        #pragma unroll
        for (int i = 0; i < 4; ++i) n2buf[w][16 * i + lane] = n2p[i];
    }
    __syncthreads();

    #pragma unroll
    for (int i = 0; i < 4; ++i) {
        f32x4_t n2v = *(const f32x4_t*)&n2buf[w][16 * i + lk * 4];
        float inv[4];
        #pragma unroll
        for (int r = 0; r < 4; ++r) {
            int lr = row0 + 16 * i + lk * 4 + r;
            inv[r] = 1.f / fmaxf(sqrtf(n2v[r]), 1e-12f * (float)(lr + 1));
        }
        #pragma unroll
        for (int j = 0; j < 2; ++j) {
            int col = 16 * j + lm;
            #pragma unroll
            for (int r = 0; r < 4; ++r) {
                int lr = row0 + 16 * i + lk * 4 + r;
                float v = acc[i][j][r] * inv[r];
                if (col < RDIM)
                    eout[(((size_t)(b * NHEAD + h)) * LSEQ + lr) * RDIM + col] = v;
                sbf[((size_t)(b * LSEQ + lr)) * 1024 + h * 64 + z * 32 + col] =
                    (col < RDIM) ? f2bf(v) : (unsigned short)0;
            }
        }
    }
}

// ---------------- host launcher ----------------
extern "C" void kernel_launch(void* const* d_in, const int* in_sizes, int n_in,
                              void* d_out, int out_size, void* d_ws, size_t ws_size,
                              hipStream_t stream)
{
    const float* queries = (const float*)d_in[0];
    const float* keys    = (const float*)d_in[1];
    const float* Wq = (const float*)d_in[3];
    const float* bq = (const float*)d_in[4];
    const float* Wk = (const float*)d_in[5];
    const float* bk = (const float*)d_in[6];
    const float* We = (const float*)d_in[7];
    const float* Wr = (const float*)d_in[8];
    const float* Lam = (const float*)d_in[9];
    const float* Wc = (const float*)d_in[10];
    const float* bc = (const float*)d_in[11];
    const float* Wo = (const float*)d_in[12];
    const float* bo = (const float*)d_in[13];

    float* out = (float*)d_out;                        // [B,L,D]
    float* escore = out + (size_t)16777216;            // [B,H,L,R]
    float* rscore = out + (size_t)24641536;            // [B,H,L,R]
    float* lam_out = out + (size_t)32505856;           // [H,R]

    char* ws = (char*)d_ws;
    unsigned short* Qb  = (unsigned short*)ws;                    // 32 MiB bf16 [B,L,D]
    unsigned short* Kb  = (unsigned short*)(ws + 33554432);       // 32 MiB
    unsigned short* sbf = (unsigned short*)(ws + 67108864);       // 32 MiB bf16 scores
    unsigned short* WqT = (unsigned short*)(ws + 100663296);      // 2 MiB
    unsigned short* WkT = (unsigned short*)(ws + 102760448);      // 2 MiB
    unsigned short* WfT = (unsigned short*)(ws + 104857600);      // 2 MiB
    float* bias2 = (float*)(ws + 106954752);                      // 4 KiB
    float* partQ = (float*)(ws + 106958848);                      // 512 KiB
    float* partK = (float*)(ws + 107483136);                      // 512 KiB
    unsigned short* WeP = (unsigned short*)(ws + 108007424);      // 64 KiB packed
    unsigned short* WrP = (unsigned short*)(ws + 108072960);      // 64 KiB
    // total ws use: ~108.2 MiB

    dim3 tb(32, 8);
    transpose_cvt_kernel<<<dim3(32, 32), tb, 0, stream>>>(Wq, WqT, DMODEL, DMODEL);
    transpose_cvt_kernel<<<dim3(32, 32), tb, 0, stream>>>(Wk, WkT, DMODEL, DMODEL);
    wpack_kernel<<<dim3(16, 2), 256, 0, stream>>>(We, Wr, WeP, WrP);
    wfold_kernel<<<dim3(16, 16), 256, 0, stream>>>(Wc, Wo, WfT);
    bias2_kernel<<<4, 256, 0, stream>>>(Wo, bc, bo, bias2);

    gemm_kernel<true, true><<<dim3(128, 8), 256, 0, stream>>>(queries, WqT, bq, Qb, 16384, 1024, 1024);
    gemm_kernel<true, true><<<dim3(128, 8), 256, 0, stream>>>(keys, WkT, bk, Kb, 16384, 1024, 1024);

    cumsum_local_kernel<<<dim3(NCHUNK, 8), 256, 0, stream>>>(Qb, Kb, partQ, partK);
    chunk_offsets_kernel<<<dim3(16, 2), 256, 0, stream>>>(partQ, partK);

    score_kernel<<<dim3(16, 64, 2), 256, 0, stream>>>(Qb, Kb, partQ, partK, WeP, WrP,
                                                      escore, rscore, sbf);

    gemm_kernel<false, false><<<dim3(128, 8), 256, 0, stream>>>(sbf, WfT, bias2, out, 16384, 1024, 1024);

    hipMemcpyAsync(lam_out, Lam, 480 * sizeof(float), hipMemcpyDeviceToDevice, stream);
}

// Round 4
// 311.802 us; speedup vs baseline: 1.5220x; 1.0373x over previous
//
#include <hip/hip_runtime.h>
#include <hip/hip_bf16.h>

#define BATCH 4
#define LSEQ 4096
#define DMODEL 1024
#define NHEAD 16
#define RDIM 30
#define DKH 64
#define NCHUNK 32
#define CHUNK 128

typedef __attribute__((ext_vector_type(8))) short bf16x8_t;
typedef __attribute__((ext_vector_type(4))) float f32x4_t;

static __device__ __forceinline__ unsigned short f2bf(float f) {
    __hip_bfloat16 h = __float2bfloat16(f);
    unsigned short u;
    __builtin_memcpy(&u, &h, 2);
    return u;
}
static __device__ __forceinline__ float b2f(unsigned short u) {
    unsigned v = ((unsigned)u) << 16;
    float f;
    __builtin_memcpy(&f, &v, 4);
    return f;
}

// ---------------- transpose + convert: W (K,N) f32 -> Wt (N,K) bf16 ----------------
__global__ void transpose_cvt_kernel(const float* __restrict__ W, unsigned short* __restrict__ outT,
                                     int Kd, int Nd) {
    __shared__ float tile[32][33];
    int n0 = blockIdx.x * 32, k0 = blockIdx.y * 32;
    int tx = threadIdx.x, ty = threadIdx.y;
    #pragma unroll
    for (int r = ty; r < 32; r += 8)
        tile[r][tx] = W[(size_t)(k0 + r) * Nd + n0 + tx];
    __syncthreads();
    #pragma unroll
    for (int r = ty; r < 32; r += 8)
        outT[(size_t)(n0 + r) * Kd + k0 + tx] = f2bf(tile[tx][r]);
}

// ---------------- pack We/Wr [H][64][30] f32 -> WP [H][32 cols][64 k] bf16 ----------------
__global__ void wpack_kernel(const float* __restrict__ We, const float* __restrict__ Wr,
                             unsigned short* __restrict__ WeP, unsigned short* __restrict__ WrP) {
    int h = blockIdx.x;
    const float* W = blockIdx.y ? Wr : We;
    unsigned short* O = blockIdx.y ? WrP : WeP;
    for (int idx = threadIdx.x; idx < 2048; idx += 256) {
        int col = idx >> 6, k = idx & 63;
        float v = (col < RDIM) ? W[((size_t)h * 64 + k) * RDIM + col] : 0.f;
        O[((size_t)h << 11) + idx] = f2bf(v);
    }
}

// ---------------- WfoldT[n][h*64+j] = sum_dk Wc[jr][dk] * Wo[h*64+dk][n]  (bf16) ----------------
__global__ __launch_bounds__(256) void wfold_kernel(
    const float* __restrict__ Wc, const float* __restrict__ Wo,
    unsigned short* __restrict__ WfoldT)
{
    __shared__ float WoT[64][65];
    __shared__ float WcT[64][61];
    const int tid = threadIdx.x;
    const int n0 = blockIdx.x * 64, h = blockIdx.y;
    for (int i = tid; i < 4096; i += 256) {
        int dk = i >> 6, n = i & 63;
        WoT[dk][n] = Wo[(size_t)(h * 64 + dk) * DMODEL + n0 + n];
    }
    for (int i = tid; i < 3840; i += 256) {
        int j = i >> 6, dk = i & 63;
        WcT[dk][j] = Wc[j * 64 + dk];
    }
    __syncthreads();
    #pragma unroll 1
    for (int oo = 0; oo < 16; ++oo) {
        int n = (tid >> 6) + oo * 4;
        int j = tid & 63;
        int jr = (j < 30) ? j : (j >= 32 && j < 62) ? (j - 2) : -1;
        float acc = 0.f;
        if (jr >= 0) {
            #pragma unroll
            for (int dk = 0; dk < 64; ++dk)
                acc = fmaf(WcT[dk][jr], WoT[dk][n], acc);
        }
        WfoldT[(size_t)(n0 + n) * 1024 + h * 64 + j] = f2bf(acc);
    }
}

// ---------------- bias2[n] = bo[n] + sum_d bc[d&63]*Wo[d][n] ----------------
__global__ void bias2_kernel(const float* __restrict__ Wo, const float* __restrict__ bc,
                             const float* __restrict__ bo, float* __restrict__ bias2) {
    int n = blockIdx.x * 256 + threadIdx.x;
    float a = bo[n];
    for (int d = 0; d < DMODEL; ++d)
        a = fmaf(bc[d & 63], Wo[(size_t)d * DMODEL + n], a);
    bias2[n] = a;
}

// ---------------- bf16 MFMA GEMM, double-buffered prefetch (T3 minimum 2-phase) ----------------
#define BM 128
#define BN 128
#define BKT 64
#define TILE_SH 8192   // BM*BKT elements

template <bool AF32, bool BF16_OUT>
__global__ __launch_bounds__(256) void gemm_kernel(
    const void* __restrict__ Av0, const void* __restrict__ Av1,
    const unsigned short* __restrict__ Bt0, const unsigned short* __restrict__ Bt1,
    const float* __restrict__ bias0, const float* __restrict__ bias1,
    void* __restrict__ Cv0, void* __restrict__ Cv1,
    int M, int N, int K)
{
    __shared__ __align__(16) unsigned short As[2][TILE_SH];
    __shared__ __align__(16) unsigned short Bs[2][TILE_SH];
    const int tid = threadIdx.x;
    const int lane = tid & 63;
    const int wid = tid >> 6;
    const int wm = wid >> 1, wn = wid & 1;
    const int bm = blockIdx.x, bn = blockIdx.y;
    const int z = blockIdx.z;
    const int lm = lane & 15;
    const int kb = lane >> 4;

    const void* Av = z ? Av1 : Av0;
    const unsigned short* Bt = z ? Bt1 : Bt0;
    const float* bias = z ? bias1 : bias0;
    void* Cv = z ? Cv1 : Cv0;

    const unsigned short* Bt_tile = Bt + (size_t)(bn * BN) * K;
    // staging geometry (shared by A-bf16 and B): per wave 4x 1KB segments
    const int s_base = (wid * 4) << 10;
    int srow[4], scc[4];
    #pragma unroll
    for (int is = 0; is < 4; ++is) {
        int s = s_base + (is << 10) + (lane << 4);
        srow[is] = s >> 7;
        scc[is] = ((s >> 4) & 7) ^ (srow[is] & 7);   // T2: pre-swizzled source, linear dest
    }

    // A f32 reg-staging geometry
    const float* A32_tile = nullptr;
    const unsigned short* A16_tile = nullptr;
    if constexpr (AF32) A32_tile = (const float*)Av + (size_t)(bm * BM) * K;
    else                A16_tile = (const unsigned short*)Av + (size_t)(bm * BM) * K;
    const int arow_base = wid * 32 + (lane >> 4);
    const int af4 = lane & 15;
    float4 areg[8];

    f32x4_t acc[4][4];
    #pragma unroll
    for (int i = 0; i < 4; ++i)
        #pragma unroll
        for (int j = 0; j < 4; ++j)
            acc[i][j] = f32x4_t{0.f, 0.f, 0.f, 0.f};

    const int NT = K / BKT;

    // ---- prologue: stage tile 0 ----
    #pragma unroll
    for (int is = 0; is < 4; ++is) {
        const unsigned short* gb = Bt_tile + (size_t)srow[is] * K + scc[is] * 8;
        __builtin_amdgcn_global_load_lds(
            (const __attribute__((address_space(1))) void*)gb,
            (__attribute__((address_space(3))) void*)((char*)Bs[0] + s_base + (is << 10)),
            16, 0, 0);
        if constexpr (!AF32) {
            const unsigned short* ga = A16_tile + (size_t)srow[is] * K + scc[is] * 8;
            __builtin_amdgcn_global_load_lds(
                (const __attribute__((address_space(1))) void*)ga,
                (__attribute__((address_space(3))) void*)((char*)As[0] + s_base + (is << 10)),
                16, 0, 0);
        }
    }
    if constexpr (AF32) {
        #pragma unroll
        for (int p = 0; p < 8; ++p)
            areg[p] = *(const float4*)(A32_tile + (size_t)(arow_base + p * 4) * K + af4 * 4);
        #pragma unroll
        for (int p = 0; p < 8; ++p) {
            int row = arow_base + p * 4;
            ushort4 pk;
            pk.x = f2bf(areg[p].x); pk.y = f2bf(areg[p].y); pk.z = f2bf(areg[p].z); pk.w = f2bf(areg[p].w);
            int kc = af4 >> 1;
            *(ushort4*)((char*)As[0] + row * 128 + ((kc ^ (row & 7)) << 4) + (af4 & 1) * 8) = pk;
        }
    }
    __syncthreads();

    int cur = 0;
    for (int t = 0; t < NT; ++t) {
        const int nxt = cur ^ 1;
        const bool more = (t + 1 < NT);
        const int k1 = (t + 1) * BKT;

        // ---- issue next tile's loads FIRST (overlap with compute) ----
        if (more) {
            #pragma unroll
            for (int is = 0; is < 4; ++is) {
                const unsigned short* gb = Bt_tile + (size_t)srow[is] * K + k1 + scc[is] * 8;
                __builtin_amdgcn_global_load_lds(
                    (const __attribute__((address_space(1))) void*)gb,
                    (__attribute__((address_space(3))) void*)((char*)Bs[nxt] + s_base + (is << 10)),
                    16, 0, 0);
                if constexpr (!AF32) {
                    const unsigned short* ga = A16_tile + (size_t)srow[is] * K + k1 + scc[is] * 8;
                    __builtin_amdgcn_global_load_lds(
                        (const __attribute__((address_space(1))) void*)ga,
                        (__attribute__((address_space(3))) void*)((char*)As[nxt] + s_base + (is << 10)),
                        16, 0, 0);
                }
            }
            if constexpr (AF32) {
                #pragma unroll
                for (int p = 0; p < 8; ++p)
                    areg[p] = *(const float4*)(A32_tile + (size_t)(arow_base + p * 4) * K + k1 + af4 * 4);
            }
        }

        // ---- compute current tile ----
        #pragma unroll
        for (int ks = 0; ks < 2; ++ks) {
            bf16x8_t af[4], bfr[4];
            #pragma unroll
            for (int i = 0; i < 4; ++i) {
                int row = wm * 64 + i * 16 + lm;
                int cc = (ks * 4 + kb) ^ (row & 7);
                af[i] = *(const bf16x8_t*)((const char*)As[cur] + row * 128 + cc * 16);
            }
            #pragma unroll
            for (int j = 0; j < 4; ++j) {
                int row = wn * 64 + j * 16 + lm;
                int cc = (ks * 4 + kb) ^ (row & 7);
                bfr[j] = *(const bf16x8_t*)((const char*)Bs[cur] + row * 128 + cc * 16);
            }
            #pragma unroll
            for (int i = 0; i < 4; ++i)
                #pragma unroll
                for (int j = 0; j < 4; ++j)
                    acc[i][j] = __builtin_amdgcn_mfma_f32_16x16x32_bf16(af[i], bfr[j], acc[i][j], 0, 0, 0);
        }

        // ---- write-late A regs -> LDS[nxt] (AF32 path) ----
        if constexpr (AF32) {
            if (more) {
                #pragma unroll
                for (int p = 0; p < 8; ++p) {
                    int row = arow_base + p * 4;
                    ushort4 pk;
                    pk.x = f2bf(areg[p].x); pk.y = f2bf(areg[p].y); pk.z = f2bf(areg[p].z); pk.w = f2bf(areg[p].w);
                    int kc = af4 >> 1;
                    *(ushort4*)((char*)As[nxt] + row * 128 + ((kc ^ (row & 7)) << 4) + (af4 & 1) * 8) = pk;
                }
            }
        }
        __syncthreads();
        cur = nxt;
    }

    #pragma unroll
    for (int i = 0; i < 4; ++i) {
        int row = bm * BM + wm * 64 + i * 16 + (lane >> 4) * 4;
        #pragma unroll
        for (int j = 0; j < 4; ++j) {
            int col = bn * BN + wn * 64 + j * 16 + lm;
            float bv = bias[col];
            #pragma unroll
            for (int r = 0; r < 4; ++r) {
                float v = acc[i][j][r] + bv;
                if constexpr (BF16_OUT)
                    ((unsigned short*)Cv)[(size_t)(row + r) * N + col] = f2bf(v);
                else
                    ((float*)Cv)[(size_t)(row + r) * N + col] = v;
            }
        }
    }
}

// ---------------- chunk-local cumsum along L, bf16 in/out, f32 partials ----------------
__global__ __launch_bounds__(256) void cumsum_local_kernel(
    unsigned short* __restrict__ Qb, unsigned short* __restrict__ Kb,
    float* __restrict__ partQ, float* __restrict__ partK)
{
    const int tid = threadIdx.x;
    const int c = blockIdx.x;
    const int bz = blockIdx.y;
    const int b = bz >> 1;
    unsigned short* buf = (bz & 1) ? Kb : Qb;
    float* part = (bz & 1) ? partK : partQ;
    size_t base = ((size_t)(b * LSEQ + c * CHUNK)) * DMODEL + tid * 4;
    float rx = 0.f, ry = 0.f, rz = 0.f, rw = 0.f;
    #pragma unroll 4
    for (int i = 0; i < CHUNK; ++i) {
        ushort4 v = *(ushort4*)(buf + base + (size_t)i * DMODEL);
        rx += b2f(v.x); ry += b2f(v.y); rz += b2f(v.z); rw += b2f(v.w);
        ushort4 o;
        o.x = f2bf(rx); o.y = f2bf(ry); o.z = f2bf(rz); o.w = f2bf(rw);
        *(ushort4*)(buf + base + (size_t)i * DMODEL) = o;
    }
    float4 p = make_float4(rx, ry, rz, rw);
    *(float4*)(part + ((size_t)(b * NCHUNK + c)) * DMODEL + tid * 4) = p;
}

// ---------------- exclusive scan of chunk sums (in place) ----------------
__global__ void chunk_offsets_kernel(float* __restrict__ partQ, float* __restrict__ partK)
{
    int t = blockIdx.x * 256 + threadIdx.x;
    float* part = blockIdx.y ? partK : partQ;
    int b = t >> 10, d = t & 1023;
    float run = 0.f;
    #pragma unroll
    for (int c = 0; c < NCHUNK; ++c) {
        size_t idx = ((size_t)(b * NCHUNK + c)) * DMODEL + d;
        float v = part[idx];
        part[idx] = run;
        run += v;
    }
}

// ---------------- MFMA score kernel ----------------
__global__ __launch_bounds__(256) void score_kernel(
    const unsigned short* __restrict__ Qc, const unsigned short* __restrict__ Kc,
    const float* __restrict__ partQ, const float* __restrict__ partK,
    const unsigned short* __restrict__ WeP, const unsigned short* __restrict__ WrP,
    float* __restrict__ escore, float* __restrict__ rscore,
    unsigned short* __restrict__ sbf)
{
    __shared__ float n2buf[4][64];
    const int tid = threadIdx.x;
    const int lane = tid & 63;
    const int w = tid >> 6;
    const int lm = lane & 15;
    const int lk = lane >> 4;
    const int c = blockIdx.x;
    const int bh = blockIdx.y;
    const int z = blockIdx.z;
    const int b = bh >> 4, h = bh & 15;
    const unsigned short* X = z ? Kc : Qc;
    const float* part = z ? partK : partQ;
    const unsigned short* WP = z ? WrP : WeP;
    float* eout = z ? rscore : escore;
    const int row0 = c * 256 + w * 64;
    const int co = c * 2 + (w >> 1);

    const float* offp = part + ((size_t)(b * NCHUNK + co)) * DMODEL + h * 64 + lk * 8;
    float o0[8], o1[8];
    {
        float4 a = *(const float4*)(offp);
        float4 bb = *(const float4*)(offp + 4);
        float4 cc = *(const float4*)(offp + 32);
        float4 dd = *(const float4*)(offp + 36);
        o0[0] = a.x; o0[1] = a.y; o0[2] = a.z; o0[3] = a.w;
        o0[4] = bb.x; o0[5] = bb.y; o0[6] = bb.z; o0[7] = bb.w;
        o1[0] = cc.x; o1[1] = cc.y; o1[2] = cc.z; o1[3] = cc.w;
        o1[4] = dd.x; o1[5] = dd.y; o1[6] = dd.z; o1[7] = dd.w;
    }

    const unsigned short* wpb = WP + ((size_t)h << 11) + lm * 64 + lk * 8;
    bf16x8_t b00 = *(const bf16x8_t*)(wpb);
    bf16x8_t b01 = *(const bf16x8_t*)(wpb + 32);
    bf16x8_t b10 = *(const bf16x8_t*)(wpb + 16 * 64);
    bf16x8_t b11 = *(const bf16x8_t*)(wpb + 16 * 64 + 32);

    f32x4_t acc[4][2];
    float n2p[4];
    #pragma unroll
    for (int i = 0; i < 4; ++i) {
        n2p[i] = 0.f;
        acc[i][0] = f32x4_t{0.f, 0.f, 0.f, 0.f};
        acc[i][1] = f32x4_t{0.f, 0.f, 0.f, 0.f};
    }

    const unsigned short* xbase = X + ((size_t)(b * LSEQ + row0 + lm)) * DMODEL + h * 64 + lk * 8;
    #pragma unroll
    for (int i = 0; i < 4; ++i) {
        const unsigned short* xp = xbase + (size_t)(16 * i) * DMODEL;
        bf16x8_t x0 = *(const bf16x8_t*)(xp);
        bf16x8_t x1 = *(const bf16x8_t*)(xp + 32);
        bf16x8_t xa0, xa1;
        #pragma unroll
        for (int j = 0; j < 8; ++j) {
            float xf = b2f((unsigned short)x0[j]) + o0[j];
            n2p[i] = fmaf(xf, xf, n2p[i]);
            xa0[j] = (short)f2bf(xf);
        }
        #pragma unroll
        for (int j = 0; j < 8; ++j) {
            float xf = b2f((unsigned short)x1[j]) + o1[j];
            n2p[i] = fmaf(xf, xf, n2p[i]);
            xa1[j] = (short)f2bf(xf);
        }
        acc[i][0] = __builtin_amdgcn_mfma_f32_16x16x32_bf16(xa0, b00, acc[i][0], 0, 0, 0);
        acc[i][1] = __builtin_amdgcn_mfma_f32_16x16x32_bf16(xa0, b10, acc[i][1], 0, 0, 0);
        acc[i][0] = __builtin_amdgcn_mfma_f32_16x16x32_bf16(xa1, b01, acc[i][0], 0, 0, 0);
        acc[i][1] = __builtin_amdgcn_mfma_f32_16x16x32_bf16(xa1, b11, acc[i][1], 0, 0, 0);
    }

    #pragma unroll
    for (int i = 0; i < 4; ++i) {
        n2p[i] += __shfl_xor(n2p[i], 16);
        n2p[i] += __shfl_xor(n2p[i], 32);
    }
    if (lane < 16) {
        #pragma unroll
        for (int i = 0; i < 4; ++i) n2buf[w][16 * i + lane] = n2p[i];
    }
    __syncthreads();

    #pragma unroll
    for (int i = 0; i < 4; ++i) {
        f32x4_t n2v = *(const f32x4_t*)&n2buf[w][16 * i + lk * 4];
        float inv[4];
        #pragma unroll
        for (int r = 0; r < 4; ++r) {
            int lr = row0 + 16 * i + lk * 4 + r;
            inv[r] = 1.f / fmaxf(sqrtf(n2v[r]), 1e-12f * (float)(lr + 1));
        }
        #pragma unroll
        for (int j = 0; j < 2; ++j) {
            int col = 16 * j + lm;
            #pragma unroll
            for (int r = 0; r < 4; ++r) {
                int lr = row0 + 16 * i + lk * 4 + r;
                float v = acc[i][j][r] * inv[r];
                if (col < RDIM)
                    eout[(((size_t)(b * NHEAD + h)) * LSEQ + lr) * RDIM + col] = v;
                sbf[((size_t)(b * LSEQ + lr)) * 1024 + h * 64 + z * 32 + col] =
                    (col < RDIM) ? f2bf(v) : (unsigned short)0;
            }
        }
    }
}

// ---------------- host launcher ----------------
extern "C" void kernel_launch(void* const* d_in, const int* in_sizes, int n_in,
                              void* d_out, int out_size, void* d_ws, size_t ws_size,
                              hipStream_t stream)
{
    const float* queries = (const float*)d_in[0];
    const float* keys    = (const float*)d_in[1];
    const float* Wq = (const float*)d_in[3];
    const float* bq = (const float*)d_in[4];
    const float* Wk = (const float*)d_in[5];
    const float* bk = (const float*)d_in[6];
    const float* We = (const float*)d_in[7];
    const float* Wr = (const float*)d_in[8];
    const float* Lam = (const float*)d_in[9];
    const float* Wc = (const float*)d_in[10];
    const float* bc = (const float*)d_in[11];
    const float* Wo = (const float*)d_in[12];
    const float* bo = (const float*)d_in[13];

    float* out = (float*)d_out;                        // [B,L,D]
    float* escore = out + (size_t)16777216;            // [B,H,L,R]
    float* rscore = out + (size_t)24641536;            // [B,H,L,R]
    float* lam_out = out + (size_t)32505856;           // [H,R]

    char* ws = (char*)d_ws;
    unsigned short* Qb  = (unsigned short*)ws;                    // 32 MiB bf16 [B,L,D]
    unsigned short* Kb  = (unsigned short*)(ws + 33554432);       // 32 MiB
    unsigned short* sbf = (unsigned short*)(ws + 67108864);       // 32 MiB bf16 scores
    unsigned short* WqT = (unsigned short*)(ws + 100663296);      // 2 MiB
    unsigned short* WkT = (unsigned short*)(ws + 102760448);      // 2 MiB
    unsigned short* WfT = (unsigned short*)(ws + 104857600);      // 2 MiB
    float* bias2 = (float*)(ws + 106954752);                      // 4 KiB
    float* partQ = (float*)(ws + 106958848);                      // 512 KiB
    float* partK = (float*)(ws + 107483136);                      // 512 KiB
    unsigned short* WeP = (unsigned short*)(ws + 108007424);      // 64 KiB packed
    unsigned short* WrP = (unsigned short*)(ws + 108072960);      // 64 KiB
    // total ws use: ~108.2 MiB

    dim3 tb(32, 8);
    transpose_cvt_kernel<<<dim3(32, 32), tb, 0, stream>>>(Wq, WqT, DMODEL, DMODEL);
    transpose_cvt_kernel<<<dim3(32, 32), tb, 0, stream>>>(Wk, WkT, DMODEL, DMODEL);
    wpack_kernel<<<dim3(16, 2), 256, 0, stream>>>(We, Wr, WeP, WrP);
    wfold_kernel<<<dim3(16, 16), 256, 0, stream>>>(Wc, Wo, WfT);
    bias2_kernel<<<4, 256, 0, stream>>>(Wo, bc, bo, bias2);

    // fused Q+K projections (z selects stream), double-buffered prefetch
    gemm_kernel<true, true><<<dim3(128, 8, 2), 256, 0, stream>>>(
        queries, keys, WqT, WkT, bq, bk, Qb, Kb, 16384, 1024, 1024);

    cumsum_local_kernel<<<dim3(NCHUNK, 8), 256, 0, stream>>>(Qb, Kb, partQ, partK);
    chunk_offsets_kernel<<<dim3(16, 2), 256, 0, stream>>>(partQ, partK);

    score_kernel<<<dim3(16, 64, 2), 256, 0, stream>>>(Qb, Kb, partQ, partK, WeP, WrP,
                                                      escore, rscore, sbf);

    gemm_kernel<false, false><<<dim3(128, 8, 1), 256, 0, stream>>>(
        sbf, sbf, WfT, WfT, bias2, bias2, out, out, 16384, 1024, 1024);

    hipMemcpyAsync(lam_out, Lam, 480 * sizeof(float), hipMemcpyDeviceToDevice, stream);
}

// Round 5
// 282.738 us; speedup vs baseline: 1.6784x; 1.1028x over previous
//
#include <hip/hip_runtime.h>
#include <hip/hip_bf16.h>

#define BATCH 4
#define LSEQ 4096
#define DMODEL 1024
#define NHEAD 16
#define RDIM 30
#define DKH 64
#define NCHUNK 32
#define CHUNK 128

typedef __attribute__((ext_vector_type(8))) short bf16x8_t;
typedef __attribute__((ext_vector_type(4))) float f32x4_t;

static __device__ __forceinline__ unsigned short f2bf(float f) {
    __hip_bfloat16 h = __float2bfloat16(f);
    unsigned short u;
    __builtin_memcpy(&u, &h, 2);
    return u;
}
static __device__ __forceinline__ float b2f(unsigned short u) {
    unsigned v = ((unsigned)u) << 16;
    float f;
    __builtin_memcpy(&f, &v, 4);
    return f;
}

#define SWAIT_VM8()   { asm volatile("s_waitcnt vmcnt(8)" ::: "memory"); __builtin_amdgcn_sched_barrier(0); }
#define SWAIT_VM0()   { asm volatile("s_waitcnt vmcnt(0)" ::: "memory"); __builtin_amdgcn_sched_barrier(0); }
#define SWAIT_LGKM0() { asm volatile("s_waitcnt lgkmcnt(0)" ::: "memory"); __builtin_amdgcn_sched_barrier(0); }
#define SBARRIER()    { __builtin_amdgcn_s_barrier(); __builtin_amdgcn_sched_barrier(0); }

// ---------------- convert f32 -> bf16 (vectorized) ----------------
__global__ void cvt_bf16_kernel(const float* __restrict__ in, unsigned short* __restrict__ out, int n4) {
    int i = blockIdx.x * blockDim.x + threadIdx.x;
    int stride = gridDim.x * blockDim.x;
    for (; i < n4; i += stride) {
        float4 v = ((const float4*)in)[i];
        ushort4 o;
        o.x = f2bf(v.x); o.y = f2bf(v.y); o.z = f2bf(v.z); o.w = f2bf(v.w);
        ((ushort4*)out)[i] = o;
    }
}

// ---------------- transpose + convert: W (K,N) f32 -> Wt (N,K) bf16 ----------------
__global__ void transpose_cvt_kernel(const float* __restrict__ W, unsigned short* __restrict__ outT,
                                     int Kd, int Nd) {
    __shared__ float tile[32][33];
    int n0 = blockIdx.x * 32, k0 = blockIdx.y * 32;
    int tx = threadIdx.x, ty = threadIdx.y;
    #pragma unroll
    for (int r = ty; r < 32; r += 8)
        tile[r][tx] = W[(size_t)(k0 + r) * Nd + n0 + tx];
    __syncthreads();
    #pragma unroll
    for (int r = ty; r < 32; r += 8)
        outT[(size_t)(n0 + r) * Kd + k0 + tx] = f2bf(tile[tx][r]);
}

// ---------------- pack We/Wr [H][64][30] f32 -> WP [H][32 cols][64 k] bf16 ----------------
__global__ void wpack_kernel(const float* __restrict__ We, const float* __restrict__ Wr,
                             unsigned short* __restrict__ WeP, unsigned short* __restrict__ WrP) {
    int h = blockIdx.x;
    const float* W = blockIdx.y ? Wr : We;
    unsigned short* O = blockIdx.y ? WrP : WeP;
    for (int idx = threadIdx.x; idx < 2048; idx += 256) {
        int col = idx >> 6, k = idx & 63;
        float v = (col < RDIM) ? W[((size_t)h * 64 + k) * RDIM + col] : 0.f;
        O[((size_t)h << 11) + idx] = f2bf(v);
    }
}

// ---------------- WfoldT[n][h*64+j] = sum_dk Wc[jr][dk] * Wo[h*64+dk][n]  (bf16) ----------------
__global__ __launch_bounds__(256) void wfold_kernel(
    const float* __restrict__ Wc, const float* __restrict__ Wo,
    unsigned short* __restrict__ WfoldT)
{
    __shared__ float WoT[64][65];
    __shared__ float WcT[64][61];
    const int tid = threadIdx.x;
    const int n0 = blockIdx.x * 64, h = blockIdx.y;
    for (int i = tid; i < 4096; i += 256) {
        int dk = i >> 6, n = i & 63;
        WoT[dk][n] = Wo[(size_t)(h * 64 + dk) * DMODEL + n0 + n];
    }
    for (int i = tid; i < 3840; i += 256) {
        int j = i >> 6, dk = i & 63;
        WcT[dk][j] = Wc[j * 64 + dk];
    }
    __syncthreads();
    #pragma unroll 1
    for (int oo = 0; oo < 16; ++oo) {
        int n = (tid >> 6) + oo * 4;
        int j = tid & 63;
        int jr = (j < 30) ? j : (j >= 32 && j < 62) ? (j - 2) : -1;
        float acc = 0.f;
        if (jr >= 0) {
            #pragma unroll
            for (int dk = 0; dk < 64; ++dk)
                acc = fmaf(WcT[dk][jr], WoT[dk][n], acc);
        }
        WfoldT[(size_t)(n0 + n) * 1024 + h * 64 + j] = f2bf(acc);
    }
}

// ---------------- bias2[n] = bo[n] + sum_d bc[d&63]*Wo[d][n] ----------------
__global__ void bias2_kernel(const float* __restrict__ Wo, const float* __restrict__ bc,
                             const float* __restrict__ bo, float* __restrict__ bias2) {
    int n = blockIdx.x * 256 + threadIdx.x;
    float a = bo[n];
    for (int d = 0; d < DMODEL; ++d)
        a = fmaf(bc[d & 63], Wo[(size_t)d * DMODEL + n], a);
    bias2[n] = a;
}

// ================= 256x256 8-wave multi-phase GEMM, K=1024 =================
// C(MxN) = A(MxK) * Bt(NxK)^T + bias.  counted-vmcnt pipeline (T3+T4), T2 swizzle,
// T5 setprio, bijective XCD chunking.  LDS 128 KiB, 1 block/CU.
#define GBM 256
#define GBN 256
#define GBK 64
#define NTILES 16   // K = 1024

template <bool BF16_OUT>
__global__ __launch_bounds__(512, 2) void gemm8_kernel(
    const unsigned short* __restrict__ A,
    const unsigned short* __restrict__ Bt,
    const float* __restrict__ bias,
    void* __restrict__ Cv,
    int M, int N)
{
    __shared__ __align__(16) unsigned short As[2][GBM * GBK];
    __shared__ __align__(16) unsigned short Bs[2][GBM * GBK];
    const int tid = threadIdx.x;
    const int lane = tid & 63;
    const int wid = tid >> 6;        // 0..7
    const int wm = wid >> 2;         // 0..1  (M half)
    const int wn = wid & 3;          // 0..3  (N quarter)
    const int lm = lane & 15;
    const int kb = lane >> 4;        // 0..3

    // bijective XCD chunking (grid.x*grid.y % 8 == 0 here: 4*64=256)
    const int nwg = gridDim.x * gridDim.y;
    const int wg = blockIdx.y * gridDim.x + blockIdx.x;
    const int cpx = nwg >> 3;
    const int swz = (wg & 7) * cpx + (wg >> 3);
    const int bn = swz % gridDim.x;
    const int bm = swz / gridDim.x;

    const unsigned short* Atile = A + (size_t)(bm * GBM) * 1024;
    const unsigned short* Btile = Bt + (size_t)(bn * GBN) * 1024;

    f32x4_t acc[8][4];
    #pragma unroll
    for (int i = 0; i < 8; ++i)
        #pragma unroll
        for (int j = 0; j < 4; ++j)
            acc[i][j] = f32x4_t{0.f, 0.f, 0.f, 0.f};

    // stage tile kt into buffer buf: 8 glld/thread (4 A-segs + 4 B-segs)
    auto STAGE = [&](int buf, int kt) {
        #pragma unroll
        for (int seg = 0; seg < 4; ++seg) {
            const int s = (seg << 13) + (tid << 4);       // byte slot 0..32767
            const int row = s >> 7;                        // 0..255
            const int cc = ((s >> 4) & 7) ^ (row & 7);     // T2: pre-swizzled source, linear dest
            const unsigned short* ga = Atile + (size_t)row * 1024 + kt * GBK + cc * 8;
            __builtin_amdgcn_global_load_lds(
                (const __attribute__((address_space(1))) void*)ga,
                (__attribute__((address_space(3))) void*)((char*)&As[buf][0] + (seg << 13) + (wid << 10)),
                16, 0, 0);
            const unsigned short* gb = Btile + (size_t)row * 1024 + kt * GBK + cc * 8;
            __builtin_amdgcn_global_load_lds(
                (const __attribute__((address_space(1))) void*)gb,
                (__attribute__((address_space(3))) void*)((char*)&Bs[buf][0] + (seg << 13) + (wid << 10)),
                16, 0, 0);
        }
    };

    bf16x8_t af[8], bfr[4];
    auto LOADFRAGS = [&](int buf, int ks) {
        #pragma unroll
        for (int i = 0; i < 8; ++i) {
            int row = wm * 128 + i * 16 + lm;
            int cc = (ks * 4 + kb) ^ (row & 7);
            af[i] = *(const bf16x8_t*)((const char*)&As[buf][0] + row * 128 + cc * 16);
        }
        #pragma unroll
        for (int j = 0; j < 4; ++j) {
            int row = wn * 64 + j * 16 + lm;
            int cc = (ks * 4 + kb) ^ (row & 7);
            bfr[j] = *(const bf16x8_t*)((const char*)&Bs[buf][0] + row * 128 + cc * 16);
        }
    };
    auto MFMAC = [&]() {
        __builtin_amdgcn_s_setprio(1);
        #pragma unroll
        for (int i = 0; i < 8; ++i)
            #pragma unroll
            for (int j = 0; j < 4; ++j)
                acc[i][j] = __builtin_amdgcn_mfma_f32_16x16x32_bf16(af[i], bfr[j], acc[i][j], 0, 0, 0);
        __builtin_amdgcn_s_setprio(0);
    };

    // ---- prologue: stage tiles 0 and 1; wait tile 0 (8 newest outstanding = tile 1) ----
    STAGE(0, 0);
    STAGE(1, 1);
    SWAIT_VM8();
    SBARRIER();

    int cur = 0;
    for (int t = 0; t < NTILES; ++t) {
        // P1: compute first K-half of tile t
        LOADFRAGS(cur, 0);
        MFMAC();
        // P2: read second K-half to regs, free buf[cur], stage tile t+2 into it, compute
        LOADFRAGS(cur, 1);
        SWAIT_LGKM0();
        SBARRIER();                      // all waves' reads of buf[cur] retired
        if (t + 2 < NTILES) STAGE(cur, t + 2);
        MFMAC();
        // P3: ensure tile t+1 landed before next iteration (counted, never 0 mid-loop)
        if (t + 1 < NTILES) {
            if (t + 2 < NTILES) { SWAIT_VM8(); }
            else                { SWAIT_VM0(); }
            SBARRIER();
        }
        cur ^= 1;
    }

    // ---- epilogue ----
    #pragma unroll
    for (int i = 0; i < 8; ++i) {
        int row = bm * GBM + wm * 128 + i * 16 + (lane >> 4) * 4;
        #pragma unroll
        for (int j = 0; j < 4; ++j) {
            int col = bn * GBN + wn * 64 + j * 16 + lm;
            float bv = bias[col];
            #pragma unroll
            for (int r = 0; r < 4; ++r) {
                float v = acc[i][j][r] + bv;
                if constexpr (BF16_OUT)
                    ((unsigned short*)Cv)[(size_t)(row + r) * N + col] = f2bf(v);
                else
                    ((float*)Cv)[(size_t)(row + r) * N + col] = v;
            }
        }
    }
}

// ---------------- chunk-local cumsum along L, bf16 in/out, f32 partials ----------------
__global__ __launch_bounds__(256) void cumsum_local_kernel(
    unsigned short* __restrict__ Qb, unsigned short* __restrict__ Kb,
    float* __restrict__ partQ, float* __restrict__ partK)
{
    const int tid = threadIdx.x;
    const int c = blockIdx.x;
    const int bz = blockIdx.y;
    const int b = bz >> 1;
    unsigned short* buf = (bz & 1) ? Kb : Qb;
    float* part = (bz & 1) ? partK : partQ;
    size_t base = ((size_t)(b * LSEQ + c * CHUNK)) * DMODEL + tid * 4;
    float rx = 0.f, ry = 0.f, rz = 0.f, rw = 0.f;
    #pragma unroll 4
    for (int i = 0; i < CHUNK; ++i) {
        ushort4 v = *(ushort4*)(buf + base + (size_t)i * DMODEL);
        rx += b2f(v.x); ry += b2f(v.y); rz += b2f(v.z); rw += b2f(v.w);
        ushort4 o;
        o.x = f2bf(rx); o.y = f2bf(ry); o.z = f2bf(rz); o.w = f2bf(rw);
        *(ushort4*)(buf + base + (size_t)i * DMODEL) = o;
    }
    float4 p = make_float4(rx, ry, rz, rw);
    *(float4*)(part + ((size_t)(b * NCHUNK + c)) * DMODEL + tid * 4) = p;
}

// ---------------- exclusive scan of chunk sums (in place) ----------------
__global__ void chunk_offsets_kernel(float* __restrict__ partQ, float* __restrict__ partK)
{
    int t = blockIdx.x * 256 + threadIdx.x;
    float* part = blockIdx.y ? partK : partQ;
    int b = t >> 10, d = t & 1023;
    float run = 0.f;
    #pragma unroll
    for (int c = 0; c < NCHUNK; ++c) {
        size_t idx = ((size_t)(b * NCHUNK + c)) * DMODEL + d;
        float v = part[idx];
        part[idx] = run;
        run += v;
    }
}

// ---------------- MFMA score kernel ----------------
__global__ __launch_bounds__(256) void score_kernel(
    const unsigned short* __restrict__ Qc, const unsigned short* __restrict__ Kc,
    const float* __restrict__ partQ, const float* __restrict__ partK,
    const unsigned short* __restrict__ WeP, const unsigned short* __restrict__ WrP,
    float* __restrict__ escore, float* __restrict__ rscore,
    unsigned short* __restrict__ sbf)
{
    __shared__ float n2buf[4][64];
    const int tid = threadIdx.x;
    const int lane = tid & 63;
    const int w = tid >> 6;
    const int lm = lane & 15;
    const int lk = lane >> 4;
    const int c = blockIdx.x;
    const int bh = blockIdx.y;
    const int z = blockIdx.z;
    const int b = bh >> 4, h = bh & 15;
    const unsigned short* X = z ? Kc : Qc;
    const float* part = z ? partK : partQ;
    const unsigned short* WP = z ? WrP : WeP;
    float* eout = z ? rscore : escore;
    const int row0 = c * 256 + w * 64;
    const int co = c * 2 + (w >> 1);

    const float* offp = part + ((size_t)(b * NCHUNK + co)) * DMODEL + h * 64 + lk * 8;
    float o0[8], o1[8];
    {
        float4 a = *(const float4*)(offp);
        float4 bb = *(const float4*)(offp + 4);
        float4 cc = *(const float4*)(offp + 32);
        float4 dd = *(const float4*)(offp + 36);
        o0[0] = a.x; o0[1] = a.y; o0[2] = a.z; o0[3] = a.w;
        o0[4] = bb.x; o0[5] = bb.y; o0[6] = bb.z; o0[7] = bb.w;
        o1[0] = cc.x; o1[1] = cc.y; o1[2] = cc.z; o1[3] = cc.w;
        o1[4] = dd.x; o1[5] = dd.y; o1[6] = dd.z; o1[7] = dd.w;
    }

    const unsigned short* wpb = WP + ((size_t)h << 11) + lm * 64 + lk * 8;
    bf16x8_t b00 = *(const bf16x8_t*)(wpb);
    bf16x8_t b01 = *(const bf16x8_t*)(wpb + 32);
    bf16x8_t b10 = *(const bf16x8_t*)(wpb + 16 * 64);
    bf16x8_t b11 = *(const bf16x8_t*)(wpb + 16 * 64 + 32);

    f32x4_t acc[4][2];
    float n2p[4];
    #pragma unroll
    for (int i = 0; i < 4; ++i) {
        n2p[i] = 0.f;
        acc[i][0] = f32x4_t{0.f, 0.f, 0.f, 0.f};
        acc[i][1] = f32x4_t{0.f, 0.f, 0.f, 0.f};
    }

    const unsigned short* xbase = X + ((size_t)(b * LSEQ + row0 + lm)) * DMODEL + h * 64 + lk * 8;
    #pragma unroll
    for (int i = 0; i < 4; ++i) {
        const unsigned short* xp = xbase + (size_t)(16 * i) * DMODEL;
        bf16x8_t x0 = *(const bf16x8_t*)(xp);
        bf16x8_t x1 = *(const bf16x8_t*)(xp + 32);
        bf16x8_t xa0, xa1;
        #pragma unroll
        for (int j = 0; j < 8; ++j) {
            float xf = b2f((unsigned short)x0[j]) + o0[j];
            n2p[i] = fmaf(xf, xf, n2p[i]);
            xa0[j] = (short)f2bf(xf);
        }
        #pragma unroll
        for (int j = 0; j < 8; ++j) {
            float xf = b2f((unsigned short)x1[j]) + o1[j];
            n2p[i] = fmaf(xf, xf, n2p[i]);
            xa1[j] = (short)f2bf(xf);
        }
        acc[i][0] = __builtin_amdgcn_mfma_f32_16x16x32_bf16(xa0, b00, acc[i][0], 0, 0, 0);
        acc[i][1] = __builtin_amdgcn_mfma_f32_16x16x32_bf16(xa0, b10, acc[i][1], 0, 0, 0);
        acc[i][0] = __builtin_amdgcn_mfma_f32_16x16x32_bf16(xa1, b01, acc[i][0], 0, 0, 0);
        acc[i][1] = __builtin_amdgcn_mfma_f32_16x16x32_bf16(xa1, b11, acc[i][1], 0, 0, 0);
    }

    #pragma unroll
    for (int i = 0; i < 4; ++i) {
        n2p[i] += __shfl_xor(n2p[i], 16);
        n2p[i] += __shfl_xor(n2p[i], 32);
    }
    if (lane < 16) {
        #pragma unroll
        for (int i = 0; i < 4; ++i) n2buf[w][16 * i + lane] = n2p[i];
    }
    __syncthreads();

    #pragma unroll
    for (int i = 0; i < 4; ++i) {
        f32x4_t n2v = *(const f32x4_t*)&n2buf[w][16 * i + lk * 4];
        float inv[4];
        #pragma unroll
        for (int r = 0; r < 4; ++r) {
            int lr = row0 + 16 * i + lk * 4 + r;
            inv[r] = 1.f / fmaxf(sqrtf(n2v[r]), 1e-12f * (float)(lr + 1));
        }
        #pragma unroll
        for (int j = 0; j < 2; ++j) {
            int col = 16 * j + lm;
            #pragma unroll
            for (int r = 0; r < 4; ++r) {
                int lr = row0 + 16 * i + lk * 4 + r;
                float v = acc[i][j][r] * inv[r];
                if (col < RDIM)
                    eout[(((size_t)(b * NHEAD + h)) * LSEQ + lr) * RDIM + col] = v;
                sbf[((size_t)(b * LSEQ + lr)) * 1024 + h * 64 + z * 32 + col] =
                    (col < RDIM) ? f2bf(v) : (unsigned short)0;
            }
        }
    }
}

// ---------------- host launcher ----------------
extern "C" void kernel_launch(void* const* d_in, const int* in_sizes, int n_in,
                              void* d_out, int out_size, void* d_ws, size_t ws_size,
                              hipStream_t stream)
{
    const float* queries = (const float*)d_in[0];
    const float* keys    = (const float*)d_in[1];
    const float* Wq = (const float*)d_in[3];
    const float* bq = (const float*)d_in[4];
    const float* Wk = (const float*)d_in[5];
    const float* bk = (const float*)d_in[6];
    const float* We = (const float*)d_in[7];
    const float* Wr = (const float*)d_in[8];
    const float* Lam = (const float*)d_in[9];
    const float* Wc = (const float*)d_in[10];
    const float* bc = (const float*)d_in[11];
    const float* Wo = (const float*)d_in[12];
    const float* bo = (const float*)d_in[13];

    float* out = (float*)d_out;                        // [B,L,D]
    float* escore = out + (size_t)16777216;            // [B,H,L,R]
    float* rscore = out + (size_t)24641536;            // [B,H,L,R]
    float* lam_out = out + (size_t)32505856;           // [H,R]

    char* ws = (char*)d_ws;
    unsigned short* tmp = (unsigned short*)ws;                    // 32 MiB: qbf, then kbf, then sbf
    unsigned short* Qb  = (unsigned short*)(ws + 33554432);       // 32 MiB bf16 [B,L,D]
    unsigned short* Kb  = (unsigned short*)(ws + 67108864);       // 32 MiB
    unsigned short* WqT = (unsigned short*)(ws + 100663296);      // 2 MiB
    unsigned short* WkT = (unsigned short*)(ws + 102760448);      // 2 MiB
    unsigned short* WfT = (unsigned short*)(ws + 104857600);      // 2 MiB
    float* bias2 = (float*)(ws + 106954752);                      // 4 KiB
    float* partQ = (float*)(ws + 106958848);                      // 512 KiB
    float* partK = (float*)(ws + 107483136);                      // 512 KiB
    unsigned short* WeP = (unsigned short*)(ws + 108007424);      // 64 KiB
    unsigned short* WrP = (unsigned short*)(ws + 108072960);      // 64 KiB
    // total ws use: ~103.2 MiB (same footprint class as proven rounds)

    const int NELEM4 = 16777216 / 4;

    dim3 tb(32, 8);
    transpose_cvt_kernel<<<dim3(32, 32), tb, 0, stream>>>(Wq, WqT, DMODEL, DMODEL);
    transpose_cvt_kernel<<<dim3(32, 32), tb, 0, stream>>>(Wk, WkT, DMODEL, DMODEL);
    wpack_kernel<<<dim3(16, 2), 256, 0, stream>>>(We, Wr, WeP, WrP);
    wfold_kernel<<<dim3(16, 16), 256, 0, stream>>>(Wc, Wo, WfT);
    bias2_kernel<<<4, 256, 0, stream>>>(Wo, bc, bo, bias2);

    // Q projection
    cvt_bf16_kernel<<<2048, 256, 0, stream>>>(queries, tmp, NELEM4);
    gemm8_kernel<true><<<dim3(4, 64), 512, 0, stream>>>(tmp, WqT, bq, Qb, 16384, 1024);
    // K projection (tmp reused; stream-ordered)
    cvt_bf16_kernel<<<2048, 256, 0, stream>>>(keys, tmp, NELEM4);
    gemm8_kernel<true><<<dim3(4, 64), 512, 0, stream>>>(tmp, WkT, bk, Kb, 16384, 1024);

    cumsum_local_kernel<<<dim3(NCHUNK, 8), 256, 0, stream>>>(Qb, Kb, partQ, partK);
    chunk_offsets_kernel<<<dim3(16, 2), 256, 0, stream>>>(partQ, partK);

    // scores (sbf reuses tmp region — q/k staging已 consumed)
    score_kernel<<<dim3(16, 64, 2), 256, 0, stream>>>(Qb, Kb, partQ, partK, WeP, WrP,
                                                      escore, rscore, tmp);

    gemm8_kernel<false><<<dim3(4, 64), 512, 0, stream>>>(tmp, WfT, bias2, out, 16384, 1024);

    hipMemcpyAsync(lam_out, Lam, 480 * sizeof(float), hipMemcpyDeviceToDevice, stream);
}

// Round 6
// 277.071 us; speedup vs baseline: 1.7128x; 1.0205x over previous
//
#include <hip/hip_runtime.h>
#include <hip/hip_bf16.h>

#define BATCH 4
#define LSEQ 4096
#define DMODEL 1024
#define NHEAD 16
#define RDIM 30
#define DKH 64
#define NCHUNK 32
#define CHUNK 128

typedef __attribute__((ext_vector_type(8))) short bf16x8_t;
typedef __attribute__((ext_vector_type(4))) float f32x4_t;

static __device__ __forceinline__ unsigned short f2bf(float f) {
    __hip_bfloat16 h = __float2bfloat16(f);
    unsigned short u;
    __builtin_memcpy(&u, &h, 2);
    return u;
}
static __device__ __forceinline__ float b2f(unsigned short u) {
    unsigned v = ((unsigned)u) << 16;
    float f;
    __builtin_memcpy(&f, &v, 4);
    return f;
}

#define SWAIT_VM8()   { asm volatile("s_waitcnt vmcnt(8)" ::: "memory"); __builtin_amdgcn_sched_barrier(0); }
#define SWAIT_VM4()   { asm volatile("s_waitcnt vmcnt(4)" ::: "memory"); __builtin_amdgcn_sched_barrier(0); }
#define SWAIT_VM0()   { asm volatile("s_waitcnt vmcnt(0)" ::: "memory"); __builtin_amdgcn_sched_barrier(0); }
#define SWAIT_LGKM0() { asm volatile("s_waitcnt lgkmcnt(0)" ::: "memory"); __builtin_amdgcn_sched_barrier(0); }
#define SBARRIER()    { __builtin_amdgcn_s_barrier(); __builtin_amdgcn_sched_barrier(0); }

// ---------------- transpose + convert: W (K,N) f32 -> Wt (N,K) bf16 ----------------
__global__ void transpose_cvt_kernel(const float* __restrict__ W, unsigned short* __restrict__ outT,
                                     int Kd, int Nd) {
    __shared__ float tile[32][33];
    int n0 = blockIdx.x * 32, k0 = blockIdx.y * 32;
    int tx = threadIdx.x, ty = threadIdx.y;
    #pragma unroll
    for (int r = ty; r < 32; r += 8)
        tile[r][tx] = W[(size_t)(k0 + r) * Nd + n0 + tx];
    __syncthreads();
    #pragma unroll
    for (int r = ty; r < 32; r += 8)
        outT[(size_t)(n0 + r) * Kd + k0 + tx] = f2bf(tile[tx][r]);
}

// ---------------- pack We/Wr [H][64][30] f32 -> WP [H][32 cols][64 k] bf16 ----------------
__global__ void wpack_kernel(const float* __restrict__ We, const float* __restrict__ Wr,
                             unsigned short* __restrict__ WeP, unsigned short* __restrict__ WrP) {
    int h = blockIdx.x;
    const float* W = blockIdx.y ? Wr : We;
    unsigned short* O = blockIdx.y ? WrP : WeP;
    for (int idx = threadIdx.x; idx < 2048; idx += 256) {
        int col = idx >> 6, k = idx & 63;
        float v = (col < RDIM) ? W[((size_t)h * 64 + k) * RDIM + col] : 0.f;
        O[((size_t)h << 11) + idx] = f2bf(v);
    }
}

// ---------------- WfoldT[n][h*64+j] = sum_dk Wc[jr][dk] * Wo[h*64+dk][n]  (bf16) ----------------
__global__ __launch_bounds__(256) void wfold_kernel(
    const float* __restrict__ Wc, const float* __restrict__ Wo,
    unsigned short* __restrict__ WfoldT)
{
    __shared__ float WoT[64][65];
    __shared__ float WcT[64][61];
    const int tid = threadIdx.x;
    const int n0 = blockIdx.x * 64, h = blockIdx.y;
    for (int i = tid; i < 4096; i += 256) {
        int dk = i >> 6, n = i & 63;
        WoT[dk][n] = Wo[(size_t)(h * 64 + dk) * DMODEL + n0 + n];
    }
    for (int i = tid; i < 3840; i += 256) {
        int j = i >> 6, dk = i & 63;
        WcT[dk][j] = Wc[j * 64 + dk];
    }
    __syncthreads();
    #pragma unroll 1
    for (int oo = 0; oo < 16; ++oo) {
        int n = (tid >> 6) + oo * 4;
        int j = tid & 63;
        int jr = (j < 30) ? j : (j >= 32 && j < 62) ? (j - 2) : -1;
        float acc = 0.f;
        if (jr >= 0) {
            #pragma unroll
            for (int dk = 0; dk < 64; ++dk)
                acc = fmaf(WcT[dk][jr], WoT[dk][n], acc);
        }
        WfoldT[(size_t)(n0 + n) * 1024 + h * 64 + j] = f2bf(acc);
    }
}

// ---------------- bias2[n] = bo[n] + sum_d bc[d&63]*Wo[d][n] ----------------
__global__ void bias2_kernel(const float* __restrict__ Wo, const float* __restrict__ bc,
                             const float* __restrict__ bo, float* __restrict__ bias2) {
    int n = blockIdx.x * 256 + threadIdx.x;
    float a = bo[n];
    for (int d = 0; d < DMODEL; ++d)
        a = fmaf(bc[d & 63], Wo[(size_t)d * DMODEL + n], a);
    bias2[n] = a;
}

// ================= 256x256 8-wave counted-vmcnt GEMM, K=1024 =================
// AF32: A is f32, reg-staged (issue-early / cvt+ds_write-late, T14) riding the
// same vmcnt ledger.  !AF32: A bf16 via global_load_lds (proven R5 schedule).
#define GBM 256
#define GBN 256
#define GBK 64
#define NTILES 16   // K = 1024

template <bool AF32, bool BF16_OUT>
__global__ __launch_bounds__(512, 2) void gemm8_kernel(
    const void* __restrict__ Av0, const void* __restrict__ Av1,
    const unsigned short* __restrict__ Bt0, const unsigned short* __restrict__ Bt1,
    const float* __restrict__ bias0, const float* __restrict__ bias1,
    void* __restrict__ Cv0, void* __restrict__ Cv1,
    int N)
{
    __shared__ __align__(16) unsigned short As[2][GBM * GBK];
    __shared__ __align__(16) unsigned short Bs[2][GBM * GBK];
    const int tid = threadIdx.x;
    const int lane = tid & 63;
    const int wid = tid >> 6;        // 0..7
    const int wm = wid >> 2;         // 0..1  (M half)
    const int wn = wid & 3;          // 0..3  (N quarter)
    const int lm = lane & 15;
    const int kb = lane >> 4;        // 0..3
    const int z = blockIdx.z;

    const void* Av = z ? Av1 : Av0;
    const unsigned short* Bt = z ? Bt1 : Bt0;
    const float* bias = z ? bias1 : bias0;
    void* Cv = z ? Cv1 : Cv0;

    // bijective XCD chunking per z-slice (nwg = 4*64 = 256, %8 == 0)
    const int nwg = gridDim.x * gridDim.y;
    const int wg = blockIdx.y * gridDim.x + blockIdx.x;
    const int cpx = nwg >> 3;
    const int swz = (wg & 7) * cpx + (wg >> 3);
    const int bn = swz % gridDim.x;
    const int bm = swz / gridDim.x;

    const unsigned short* Btile = Bt + (size_t)(bn * GBN) * 1024;
    const float* A32_tile = nullptr;
    const unsigned short* A16_tile = nullptr;
    if constexpr (AF32) A32_tile = (const float*)Av + (size_t)(bm * GBM) * 1024;
    else                A16_tile = (const unsigned short*)Av + (size_t)(bm * GBM) * 1024;

    f32x4_t acc[8][4];
    #pragma unroll
    for (int i = 0; i < 8; ++i)
        #pragma unroll
        for (int j = 0; j < 4; ++j)
            acc[i][j] = f32x4_t{0.f, 0.f, 0.f, 0.f};

    // ---- B staging: 4 glld/thread (32 KB tile) ----
    auto B_STAGE = [&](int buf, int kt) {
        #pragma unroll
        for (int seg = 0; seg < 4; ++seg) {
            const int s = (seg << 13) + (tid << 4);
            const int row = s >> 7;
            const int cc = ((s >> 4) & 7) ^ (row & 7);   // T2 pre-swizzled source, linear dest
            const unsigned short* gb = Btile + (size_t)row * 1024 + kt * GBK + cc * 8;
            __builtin_amdgcn_global_load_lds(
                (const __attribute__((address_space(1))) void*)gb,
                (__attribute__((address_space(3))) void*)((char*)&Bs[buf][0] + (seg << 13) + (wid << 10)),
                16, 0, 0);
        }
    };
    // ---- A staging, bf16 path: 4 glld/thread ----
    auto A_STAGE16 = [&](int buf, int kt) {
        #pragma unroll
        for (int seg = 0; seg < 4; ++seg) {
            const int s = (seg << 13) + (tid << 4);
            const int row = s >> 7;
            const int cc = ((s >> 4) & 7) ^ (row & 7);
            const unsigned short* ga = A16_tile + (size_t)row * 1024 + kt * GBK + cc * 8;
            __builtin_amdgcn_global_load_lds(
                (const __attribute__((address_space(1))) void*)ga,
                (__attribute__((address_space(3))) void*)((char*)&As[buf][0] + (seg << 13) + (wid << 10)),
                16, 0, 0);
        }
    };
    // ---- A staging, f32 path: 8 float4 loads -> areg (issue-early) ----
    float4 areg[8];
    auto A_ISSUE = [&](int kt) {
        #pragma unroll
        for (int p = 0; p < 8; ++p) {
            int q = p * 512 + tid;            // flat quad index
            int row = q >> 4, kq = q & 15;    // row 0..255, f32-quad 0..15
            areg[p] = *(const float4*)(A32_tile + (size_t)row * 1024 + kt * GBK + kq * 4);
        }
    };
    // ---- cvt + ds_write to the SAME swizzled slots the reads expect (write-late) ----
    auto A_WRITE = [&](int buf) {
        #pragma unroll
        for (int p = 0; p < 8; ++p) {
            int q = p * 512 + tid;
            int row = q >> 4, kq = q & 15;
            ushort4 pk;
            pk.x = f2bf(areg[p].x); pk.y = f2bf(areg[p].y);
            pk.z = f2bf(areg[p].z); pk.w = f2bf(areg[p].w);
            int cc = (kq >> 1) ^ (row & 7);
            *(ushort4*)((char*)&As[buf][0] + row * 128 + (cc << 4) + (kq & 1) * 8) = pk;
        }
    };

    bf16x8_t af[8], bfr[4];
    auto LOADFRAGS = [&](int buf, int ks) {
        #pragma unroll
        for (int i = 0; i < 8; ++i) {
            int row = wm * 128 + i * 16 + lm;
            int cc = (ks * 4 + kb) ^ (row & 7);
            af[i] = *(const bf16x8_t*)((const char*)&As[buf][0] + row * 128 + cc * 16);
        }
        #pragma unroll
        for (int j = 0; j < 4; ++j) {
            int row = wn * 64 + j * 16 + lm;
            int cc = (ks * 4 + kb) ^ (row & 7);
            bfr[j] = *(const bf16x8_t*)((const char*)&Bs[buf][0] + row * 128 + cc * 16);
        }
    };
    auto MFMAC = [&]() {
        __builtin_amdgcn_s_setprio(1);
        #pragma unroll
        for (int i = 0; i < 8; ++i)
            #pragma unroll
            for (int j = 0; j < 4; ++j)
                acc[i][j] = __builtin_amdgcn_mfma_f32_16x16x32_bf16(af[i], bfr[j], acc[i][j], 0, 0, 0);
        __builtin_amdgcn_s_setprio(0);
    };

    // ---- prologue ----
    if constexpr (AF32) {
        B_STAGE(0, 0);
        A_ISSUE(0);
        SWAIT_VM0();                  // B0 in LDS, A0 in regs (tail-free: prologue only)
        A_WRITE(0);
        B_STAGE(1, 1);
        A_ISSUE(1);                   // queue: B1(4), A1(8)
        SWAIT_LGKM0();                // A0 ds_writes visible
        SBARRIER();
    } else {
        A_STAGE16(0, 0);
        B_STAGE(0, 0);
        __builtin_amdgcn_sched_barrier(0);   // pin tile-0 loads before tile-1
        A_STAGE16(1, 1);
        B_STAGE(1, 1);
        SWAIT_VM8();                  // tile 0's 8 loads done
        SBARRIER();
    }

    int cur = 0;
    for (int t = 0; t < NTILES; ++t) {
        // P1: first K-half of tile t
        LOADFRAGS(cur, 0);
        MFMAC();
        // P2: second K-half frags, free buf[cur], stage tile t+2, compute
        LOADFRAGS(cur, 1);
        SWAIT_LGKM0();
        SBARRIER();                   // all waves done reading buf[cur]
        if constexpr (AF32) {
            if (t + 2 < NTILES) B_STAGE(cur, t + 2);       // queue: B(t+1)4, A(t+1)8, B(t+2)4
            if (t + 1 < NTILES) {
                if (t + 2 < NTILES) { SWAIT_VM4(); }       // B(t+1)+A(t+1) retired
                else                { SWAIT_VM0(); }
                A_WRITE(cur ^ 1);                           // tile t+1 A -> As[nxt]
                if (t + 2 < NTILES) A_ISSUE(t + 2);         // queue: B(t+2)4, A(t+2)8
            }
            MFMAC();
            if (t + 1 < NTILES) { SWAIT_LGKM0(); SBARRIER(); }   // publish buf[nxt]
        } else {
            if (t + 2 < NTILES) { A_STAGE16(cur, t + 2); B_STAGE(cur, t + 2); }
            MFMAC();
            if (t + 1 < NTILES) {
                if (t + 2 < NTILES) { SWAIT_VM8(); }
                else                { SWAIT_VM0(); }
                SBARRIER();
            }
        }
        cur ^= 1;
    }

    // ---- epilogue ----
    #pragma unroll
    for (int i = 0; i < 8; ++i) {
        int row = bm * GBM + wm * 128 + i * 16 + (lane >> 4) * 4;
        #pragma unroll
        for (int j = 0; j < 4; ++j) {
            int col = bn * GBN + wn * 64 + j * 16 + lm;
            float bv = bias[col];
            #pragma unroll
            for (int r = 0; r < 4; ++r) {
                float v = acc[i][j][r] + bv;
                if constexpr (BF16_OUT)
                    ((unsigned short*)Cv)[(size_t)(row + r) * N + col] = f2bf(v);
                else
                    ((float*)Cv)[(size_t)(row + r) * N + col] = v;
            }
        }
    }
}

// ---------------- chunk-local cumsum along L, bf16 in/out, f32 partials ----------------
__global__ __launch_bounds__(256) void cumsum_local_kernel(
    unsigned short* __restrict__ Qb, unsigned short* __restrict__ Kb,
    float* __restrict__ partQ, float* __restrict__ partK)
{
    const int tid = threadIdx.x;
    const int c = blockIdx.x;
    const int bz = blockIdx.y;
    const int b = bz >> 1;
    unsigned short* buf = (bz & 1) ? Kb : Qb;
    float* part = (bz & 1) ? partK : partQ;
    size_t base = ((size_t)(b * LSEQ + c * CHUNK)) * DMODEL + tid * 4;
    float rx = 0.f, ry = 0.f, rz = 0.f, rw = 0.f;
    #pragma unroll 4
    for (int i = 0; i < CHUNK; ++i) {
        ushort4 v = *(ushort4*)(buf + base + (size_t)i * DMODEL);
        rx += b2f(v.x); ry += b2f(v.y); rz += b2f(v.z); rw += b2f(v.w);
        ushort4 o;
        o.x = f2bf(rx); o.y = f2bf(ry); o.z = f2bf(rz); o.w = f2bf(rw);
        *(ushort4*)(buf + base + (size_t)i * DMODEL) = o;
    }
    float4 p = make_float4(rx, ry, rz, rw);
    *(float4*)(part + ((size_t)(b * NCHUNK + c)) * DMODEL + tid * 4) = p;
}

// ---------------- exclusive scan of chunk sums (in place) ----------------
__global__ void chunk_offsets_kernel(float* __restrict__ partQ, float* __restrict__ partK)
{
    int t = blockIdx.x * 256 + threadIdx.x;
    float* part = blockIdx.y ? partK : partQ;
    int b = t >> 10, d = t & 1023;
    float run = 0.f;
    #pragma unroll
    for (int c = 0; c < NCHUNK; ++c) {
        size_t idx = ((size_t)(b * NCHUNK + c)) * DMODEL + d;
        float v = part[idx];
        part[idx] = run;
        run += v;
    }
}

// ---------------- MFMA score kernel ----------------
__global__ __launch_bounds__(256) void score_kernel(
    const unsigned short* __restrict__ Qc, const unsigned short* __restrict__ Kc,
    const float* __restrict__ partQ, const float* __restrict__ partK,
    const unsigned short* __restrict__ WeP, const unsigned short* __restrict__ WrP,
    float* __restrict__ escore, float* __restrict__ rscore,
    unsigned short* __restrict__ sbf)
{
    __shared__ float n2buf[4][64];
    const int tid = threadIdx.x;
    const int lane = tid & 63;
    const int w = tid >> 6;
    const int lm = lane & 15;
    const int lk = lane >> 4;
    const int c = blockIdx.x;
    const int bh = blockIdx.y;
    const int z = blockIdx.z;
    const int b = bh >> 4, h = bh & 15;
    const unsigned short* X = z ? Kc : Qc;
    const float* part = z ? partK : partQ;
    const unsigned short* WP = z ? WrP : WeP;
    float* eout = z ? rscore : escore;
    const int row0 = c * 256 + w * 64;
    const int co = c * 2 + (w >> 1);

    const float* offp = part + ((size_t)(b * NCHUNK + co)) * DMODEL + h * 64 + lk * 8;
    float o0[8], o1[8];
    {
        float4 a = *(const float4*)(offp);
        float4 bb = *(const float4*)(offp + 4);
        float4 cc = *(const float4*)(offp + 32);
        float4 dd = *(const float4*)(offp + 36);
        o0[0] = a.x; o0[1] = a.y; o0[2] = a.z; o0[3] = a.w;
        o0[4] = bb.x; o0[5] = bb.y; o0[6] = bb.z; o0[7] = bb.w;
        o1[0] = cc.x; o1[1] = cc.y; o1[2] = cc.z; o1[3] = cc.w;
        o1[4] = dd.x; o1[5] = dd.y; o1[6] = dd.z; o1[7] = dd.w;
    }

    const unsigned short* wpb = WP + ((size_t)h << 11) + lm * 64 + lk * 8;
    bf16x8_t b00 = *(const bf16x8_t*)(wpb);
    bf16x8_t b01 = *(const bf16x8_t*)(wpb + 32);
    bf16x8_t b10 = *(const bf16x8_t*)(wpb + 16 * 64);
    bf16x8_t b11 = *(const bf16x8_t*)(wpb + 16 * 64 + 32);

    f32x4_t acc[4][2];
    float n2p[4];
    #pragma unroll
    for (int i = 0; i < 4; ++i) {
        n2p[i] = 0.f;
        acc[i][0] = f32x4_t{0.f, 0.f, 0.f, 0.f};
        acc[i][1] = f32x4_t{0.f, 0.f, 0.f, 0.f};
    }

    const unsigned short* xbase = X + ((size_t)(b * LSEQ + row0 + lm)) * DMODEL + h * 64 + lk * 8;
    #pragma unroll
    for (int i = 0; i < 4; ++i) {
        const unsigned short* xp = xbase + (size_t)(16 * i) * DMODEL;
        bf16x8_t x0 = *(const bf16x8_t*)(xp);
        bf16x8_t x1 = *(const bf16x8_t*)(xp + 32);
        bf16x8_t xa0, xa1;
        #pragma unroll
        for (int j = 0; j < 8; ++j) {
            float xf = b2f((unsigned short)x0[j]) + o0[j];
            n2p[i] = fmaf(xf, xf, n2p[i]);
            xa0[j] = (short)f2bf(xf);
        }
        #pragma unroll
        for (int j = 0; j < 8; ++j) {
            float xf = b2f((unsigned short)x1[j]) + o1[j];
            n2p[i] = fmaf(xf, xf, n2p[i]);
            xa1[j] = (short)f2bf(xf);
        }
        acc[i][0] = __builtin_amdgcn_mfma_f32_16x16x32_bf16(xa0, b00, acc[i][0], 0, 0, 0);
        acc[i][1] = __builtin_amdgcn_mfma_f32_16x16x32_bf16(xa0, b10, acc[i][1], 0, 0, 0);
        acc[i][0] = __builtin_amdgcn_mfma_f32_16x16x32_bf16(xa1, b01, acc[i][0], 0, 0, 0);
        acc[i][1] = __builtin_amdgcn_mfma_f32_16x16x32_bf16(xa1, b11, acc[i][1], 0, 0, 0);
    }

    #pragma unroll
    for (int i = 0; i < 4; ++i) {
        n2p[i] += __shfl_xor(n2p[i], 16);
        n2p[i] += __shfl_xor(n2p[i], 32);
    }
    if (lane < 16) {
        #pragma unroll
        for (int i = 0; i < 4; ++i) n2buf[w][16 * i + lane] = n2p[i];
    }
    __syncthreads();

    #pragma unroll
    for (int i = 0; i < 4; ++i) {
        f32x4_t n2v = *(const f32x4_t*)&n2buf[w][16 * i + lk * 4];
        float inv[4];
        #pragma unroll
        for (int r = 0; r < 4; ++r) {
            int lr = row0 + 16 * i + lk * 4 + r;
            inv[r] = 1.f / fmaxf(sqrtf(n2v[r]), 1e-12f * (float)(lr + 1));
        }
        #pragma unroll
        for (int j = 0; j < 2; ++j) {
            int col = 16 * j + lm;
            #pragma unroll
            for (int r = 0; r < 4; ++r) {
                int lr = row0 + 16 * i + lk * 4 + r;
                float v = acc[i][j][r] * inv[r];
                if (col < RDIM)
                    eout[(((size_t)(b * NHEAD + h)) * LSEQ + lr) * RDIM + col] = v;
                sbf[((size_t)(b * LSEQ + lr)) * 1024 + h * 64 + z * 32 + col] =
                    (col < RDIM) ? f2bf(v) : (unsigned short)0;
            }
        }
    }
}

// ---------------- host launcher ----------------
extern "C" void kernel_launch(void* const* d_in, const int* in_sizes, int n_in,
                              void* d_out, int out_size, void* d_ws, size_t ws_size,
                              hipStream_t stream)
{
    const float* queries = (const float*)d_in[0];
    const float* keys    = (const float*)d_in[1];
    const float* Wq = (const float*)d_in[3];
    const float* bq = (const float*)d_in[4];
    const float* Wk = (const float*)d_in[5];
    const float* bk = (const float*)d_in[6];
    const float* We = (const float*)d_in[7];
    const float* Wr = (const float*)d_in[8];
    const float* Lam = (const float*)d_in[9];
    const float* Wc = (const float*)d_in[10];
    const float* bc = (const float*)d_in[11];
    const float* Wo = (const float*)d_in[12];
    const float* bo = (const float*)d_in[13];

    float* out = (float*)d_out;                        // [B,L,D]
    float* escore = out + (size_t)16777216;            // [B,H,L,R]
    float* rscore = out + (size_t)24641536;            // [B,H,L,R]
    float* lam_out = out + (size_t)32505856;           // [H,R]

    char* ws = (char*)d_ws;
    unsigned short* sbf = (unsigned short*)ws;                    // 32 MiB bf16 scores
    unsigned short* Qb  = (unsigned short*)(ws + 33554432);       // 32 MiB bf16 [B,L,D]
    unsigned short* Kb  = (unsigned short*)(ws + 67108864);       // 32 MiB
    unsigned short* WqT = (unsigned short*)(ws + 100663296);      // 2 MiB
    unsigned short* WkT = (unsigned short*)(ws + 102760448);      // 2 MiB
    unsigned short* WfT = (unsigned short*)(ws + 104857600);      // 2 MiB
    float* bias2 = (float*)(ws + 106954752);                      // 4 KiB
    float* partQ = (float*)(ws + 106958848);                      // 512 KiB
    float* partK = (float*)(ws + 107483136);                      // 512 KiB
    unsigned short* WeP = (unsigned short*)(ws + 108007424);      // 64 KiB
    unsigned short* WrP = (unsigned short*)(ws + 108072960);      // 64 KiB
    // total ws use: ~103.2 MiB

    dim3 tb(32, 8);
    transpose_cvt_kernel<<<dim3(32, 32), tb, 0, stream>>>(Wq, WqT, DMODEL, DMODEL);
    transpose_cvt_kernel<<<dim3(32, 32), tb, 0, stream>>>(Wk, WkT, DMODEL, DMODEL);
    wpack_kernel<<<dim3(16, 2), 256, 0, stream>>>(We, Wr, WeP, WrP);
    wfold_kernel<<<dim3(16, 16), 256, 0, stream>>>(Wc, Wo, WfT);
    bias2_kernel<<<4, 256, 0, stream>>>(Wo, bc, bo, bias2);

    // fused Q+K projections: f32 A reg-staged + cvt inside the pipeline (no cvt pass)
    gemm8_kernel<true, true><<<dim3(4, 64, 2), 512, 0, stream>>>(
        queries, keys, WqT, WkT, bq, bk, Qb, Kb, 1024);

    cumsum_local_kernel<<<dim3(NCHUNK, 8), 256, 0, stream>>>(Qb, Kb, partQ, partK);
    chunk_offsets_kernel<<<dim3(16, 2), 256, 0, stream>>>(partQ, partK);

    score_kernel<<<dim3(16, 64, 2), 256, 0, stream>>>(Qb, Kb, partQ, partK, WeP, WrP,
                                                      escore, rscore, sbf);

    gemm8_kernel<false, false><<<dim3(4, 64, 1), 512, 0, stream>>>(
        sbf, sbf, WfT, WfT, bias2, bias2, out, out, 1024);

    hipMemcpyAsync(lam_out, Lam, 480 * sizeof(float), hipMemcpyDeviceToDevice, stream);
}